// Round 4
// baseline (220.860 us; speedup 1.0000x reference)
//
#include <hip/hip_runtime.h>
#include <hip/hip_bf16.h>
#include <cstdint>

typedef unsigned short u16;
typedef unsigned int u32;
typedef __bf16 bf16x8 __attribute__((ext_vector_type(8)));
typedef float f32x4 __attribute__((ext_vector_type(4)));

// ---------- helpers ----------
__device__ __forceinline__ u16 f2b(float f) {          // fp32 -> bf16 RNE
    unsigned int u = __float_as_uint(f);
    u += 0x7fffu + ((u >> 16) & 1u);
    return (u16)(u >> 16);
}
__device__ __forceinline__ float b2f(u16 h) {
    return __uint_as_float(((unsigned int)h) << 16);
}
__device__ __forceinline__ void async_cp16(void* lds, const void* g) {
    __builtin_amdgcn_global_load_lds((const __attribute__((address_space(1))) void*)g,
                                     (__attribute__((address_space(3))) void*)lds, 16, 0, 0);
}

// ================= prep kernel: cvt + transpose(f2) + transpose(f1) + three_nn =================
// blocks [0,160): W1/W2 -> bf16        (40960 float4)
// blocks [160,672): feature2 [4][256][2048] -> F2T [4][2048][256] bf16
// blocks [672,1696): feature1 [4][128][8192] -> F1T [4][8192][128] bf16
// blocks [1696,2208): three_nn, 64 queries/block, 2 queries/thread
#define NB_CVT 160
#define NB_T2  512
#define NB_T1  1024
#define NB_NN  512

__global__ __launch_bounds__(256) void prep_kernel(const float* __restrict__ w1,
                                                   const float* __restrict__ w2,
                                                   u16* __restrict__ wb,
                                                   const float* __restrict__ feature2,
                                                   u16* __restrict__ f2t,
                                                   const float* __restrict__ feature1,
                                                   u16* __restrict__ f1t,
                                                   const float* __restrict__ pos1,
                                                   const float* __restrict__ pos2,
                                                   int* __restrict__ idx_out,
                                                   float* __restrict__ w_out) {
    __shared__ __align__(16) char smem[45056];
    int bi = blockIdx.x;
    int tid = threadIdx.x;

    if (bi < NB_CVT) {
        // ---- weight conversion ----
        int i = bi * 256 + tid;
        if (i < 40960) {
            const float* src = (i < 24576) ? w1 : w2;
            int k = (i < 24576) ? i : (i - 24576);
            float4 v = *(const float4*)&src[(size_t)k * 4];
            ushort4 o;
            o.x = f2b(v.x); o.y = f2b(v.y); o.z = f2b(v.z); o.w = f2b(v.w);
            *(ushort4*)&wb[(size_t)i * 4] = o;
        }
        return;
    }
    if (bi < NB_CVT + NB_T2 + NB_T1) {
        // ---- transpose [B][C][S] -> [B][S][C] bf16 ----
        float (*t)[65] = (float (*)[65])smem;
        const float* in; u16* out; int C, S, s0, c0, b;
        if (bi < NB_CVT + NB_T2) {
            int lin = bi - NB_CVT;
            C = 256; S = 2048; in = feature2; out = f2t;
            s0 = (lin & 31) * 64; c0 = ((lin >> 5) & 3) * 64; b = lin >> 7;
        } else {
            int lin = bi - NB_CVT - NB_T2;
            C = 128; S = 8192; in = feature1; out = f1t;
            s0 = (lin & 127) * 64; c0 = ((lin >> 7) & 1) * 64; b = lin >> 8;
        }
        const float* ib = in + (size_t)b * C * S;
        u16* ob = out + (size_t)b * S * C;
        int col = tid & 63, r0 = tid >> 6;
#pragma unroll
        for (int p = 0; p < 16; ++p) {
            int c = p * 4 + r0;
            t[c][col] = ib[(size_t)(c0 + c) * S + s0 + col];
        }
        __syncthreads();
#pragma unroll
        for (int p = 0; p < 16; ++p) {
            int s = p * 4 + r0;
            ob[(size_t)(s0 + s) * C + c0 + col] = f2b(t[col][s]);
        }
        return;
    }

    // ---- three_nn: 64 queries/block, 2 queries/thread, 8 chunks of 256 cands ----
    // Track top-3 LARGEST exact fp32 t' = dot(p1,p2) - 0.5*|p2|^2 with index.
    // Strict > keeps earliest (lowest) index on exact ties, matching lax.top_k.
    float4* pk = (float4*)smem;                 // 2048 * 16 B
    float* md = (float*)(smem + 32768);         // 64*8*3 fp32
    int*   mi = (int*)(smem + 38912);           // 64*8*3 int
    int nb = bi - (NB_CVT + NB_T2 + NB_T1);
    int j0 = nb * 64;
    int b = j0 >> 13;
    const float* p2 = pos2 + (size_t)b * 3 * 2048;
    for (int i = tid; i < 2048; i += 256) {
        float x = p2[i], y = p2[2048 + i], z = p2[4096 + i];
        pk[i] = make_float4(x, y, z, -0.5f * (x * x + y * y + z * z));
    }
    __syncthreads();
    int qh = tid & 31, ck = tid >> 5;
    int na = (j0 & 8191) + qh, nbq = na + 32;
    const float* p1 = pos1 + (size_t)b * 3 * 8192;
    float xa = p1[na], ya = p1[8192 + na], za = p1[16384 + na];
    float xb = p1[nbq], yb = p1[8192 + nbq], zb = p1[16384 + nbq];

    float ga0 = -3.4e38f, ga1 = -3.4e38f, ga2 = -3.4e38f;
    float gb0 = -3.4e38f, gb1 = -3.4e38f, gb2 = -3.4e38f;
    int ia0 = 0, ia1 = 0, ia2 = 0, ib0 = 0, ib1 = 0, ib2 = 0;
    int sb = ck * 256;
    const float4* pc = pk + sb;
#pragma unroll 4
    for (int it = 0; it < 256; ++it) {
        float4 cd = pc[it];
        int s = sb + it;
        float ta = fmaf(xa, cd.x, fmaf(ya, cd.y, fmaf(za, cd.z, cd.w)));
        float tb = fmaf(xb, cd.x, fmaf(yb, cd.y, fmaf(zb, cd.z, cd.w)));
        bool a0 = ta > ga0, a1 = ta > ga1, a2 = ta > ga2;
        ga2 = a1 ? ga1 : (a2 ? ta : ga2);
        ia2 = a1 ? ia1 : (a2 ? s : ia2);
        ga1 = a0 ? ga0 : (a1 ? ta : ga1);
        ia1 = a0 ? ia0 : (a1 ? s : ia1);
        ga0 = a0 ? ta : ga0;
        ia0 = a0 ? s : ia0;
        bool b0c = tb > gb0, b1c = tb > gb1, b2c = tb > gb2;
        gb2 = b1c ? gb1 : (b2c ? tb : gb2);
        ib2 = b1c ? ib1 : (b2c ? s : ib2);
        gb1 = b0c ? gb0 : (b1c ? tb : gb1);
        ib1 = b0c ? ib0 : (b1c ? s : ib1);
        gb0 = b0c ? tb : gb0;
        ib0 = b0c ? s : ib0;
    }
    int ba = (qh * 8 + ck) * 3;
    md[ba] = ga0; md[ba + 1] = ga1; md[ba + 2] = ga2;
    mi[ba] = ia0; mi[ba + 1] = ia1; mi[ba + 2] = ia2;
    int bb = ((qh + 32) * 8 + ck) * 3;
    md[bb] = gb0; md[bb + 1] = gb1; md[bb + 2] = gb2;
    mi[bb] = ib0; mi[bb + 1] = ib1; mi[bb + 2] = ib2;
    __syncthreads();
    if (tid < 64) {
        float m0 = -3.4e38f, m1 = -3.4e38f, m2 = -3.4e38f;
        int q0 = 0, q1 = 0, q2 = 0;
        const float* vq = &md[tid * 24];
        const int* iq = &mi[tid * 24];
#pragma unroll
        for (int r = 0; r < 24; ++r) {       // chunk-ascending => index-ascending on ties
            float t = vq[r]; int s = iq[r];
            bool c0 = t > m0, c1 = t > m1, c2 = t > m2;
            m2 = c1 ? m1 : (c2 ? t : m2);
            q2 = c1 ? q1 : (c2 ? s : q2);
            m1 = c0 ? m0 : (c1 ? t : m1);
            q1 = c0 ? q0 : (c1 ? s : q1);
            m0 = c0 ? t : m0;
            q0 = c0 ? s : q0;
        }
        int j = j0 + tid;
        int n = j & 8191;
        float x1 = p1[n], y1 = p1[8192 + n], z1 = p1[16384 + n];
        float n1 = x1 * x1 + y1 * y1 + z1 * z1;
        float d0 = fmaxf(fmaf(-2.f, m0, n1), 1e-10f);
        float d1 = fmaxf(fmaf(-2.f, m1, n1), 1e-10f);
        float d2 = fmaxf(fmaf(-2.f, m2, n1), 1e-10f);
        float w0 = 1.f / d0, w1 = 1.f / d1, w2 = 1.f / d2;
        float inv = 1.f / (w0 + w1 + w2);
        idx_out[j * 3] = q0; idx_out[j * 3 + 1] = q1; idx_out[j * 3 + 2] = q2;
        w_out[j * 3] = w0 * inv; w_out[j * 3 + 1] = w1 * inv; w_out[j * 3 + 2] = w2 * inv;
    }
}

// ---------- gather + interpolate -> INTERP [32768][256] bf16 ----------
__global__ __launch_bounds__(256) void gather_kernel(const u16* __restrict__ f2t,
                                                     const int* __restrict__ idx,
                                                     const float* __restrict__ wgt,
                                                     u16* __restrict__ interp) {
    int wv = threadIdx.x >> 6, lane = threadIdx.x & 63;
    int j = blockIdx.x * 4 + wv;
    int b = j >> 13;
    int i0 = idx[j * 3], i1 = idx[j * 3 + 1], i2 = idx[j * 3 + 2];
    float w0 = wgt[j * 3], w1 = wgt[j * 3 + 1], w2 = wgt[j * 3 + 2];
    const u16* r0 = f2t + ((size_t)(b * 2048 + i0)) * 256;
    const u16* r1 = f2t + ((size_t)(b * 2048 + i1)) * 256;
    const u16* r2 = f2t + ((size_t)(b * 2048 + i2)) * 256;
    int c = lane * 4;
    ushort4 v0 = *(const ushort4*)(r0 + c);
    ushort4 v1 = *(const ushort4*)(r1 + c);
    ushort4 v2 = *(const ushort4*)(r2 + c);
    ushort4 o;
    o.x = f2b(w0 * b2f(v0.x) + w1 * b2f(v1.x) + w2 * b2f(v2.x));
    o.y = f2b(w0 * b2f(v0.y) + w1 * b2f(v1.y) + w2 * b2f(v2.y));
    o.z = f2b(w0 * b2f(v0.z) + w1 * b2f(v1.z) + w2 * b2f(v2.z));
    o.w = f2b(w0 * b2f(v0.w) + w1 * b2f(v1.w) + w2 * b2f(v2.w));
    *(ushort4*)(interp + (size_t)j * 256 + c) = o;
}

// ---------- GEMM: Yb[j][m] = bf16(sum_k A[j][k]*Bw[m][k] + bias[m]), fused BN stats ----------
// SPLIT: A = [A1 (k<256, stride 256) | A2 (k>=256, stride 128)], KT = total K
template <int KT, bool SPLIT>
__global__ __launch_bounds__(256, 2) void gemm_kernel(const u16* __restrict__ A1,
                                                      const u16* __restrict__ A2,
                                                      const u16* __restrict__ Bw,
                                                      const float* __restrict__ bias,
                                                      u16* __restrict__ Yb,
                                                      float* __restrict__ stats) {
    __shared__ u16 Al[128 * 64];
    __shared__ u16 Bl[128 * 64];
    int tid = threadIdx.x;
    int lane = tid & 63, wv = tid >> 6;
    int j0 = blockIdx.x * 128, m0 = blockIdx.y * 128;
    int l15 = lane & 15, q = lane >> 4;
    int wj = (wv >> 1) * 64, wm = (wv & 1) * 64;
    f32x4 acc[4][4];
#pragma unroll
    for (int i = 0; i < 4; ++i)
#pragma unroll
        for (int jj = 0; jj < 4; ++jj) acc[i][jj] = (f32x4){0.f, 0.f, 0.f, 0.f};

    int rbase = wv * 32;
    int lrow = lane >> 3, lchunk = lane & 7;
    const u16* Bg = Bw + (size_t)m0 * KT;

    for (int k0 = 0; k0 < KT; k0 += 64) {
        const u16* src; int stride;
        if (!SPLIT || k0 < 256) { src = A1 + (size_t)j0 * 256 + k0; stride = 256; }
        else                    { src = A2 + (size_t)j0 * 128 + (k0 - 256); stride = 128; }
#pragma unroll
        for (int qq = 0; qq < 4; ++qq) {
            int row = rbase + qq * 8;   // wave-uniform LDS base; HW adds lane*16B
            async_cp16(&Al[row * 64], src + (size_t)(row + lrow) * stride + lchunk * 8);
            async_cp16(&Bl[row * 64], Bg + (size_t)(row + lrow) * KT + k0 + lchunk * 8);
        }
        __syncthreads();
#pragma unroll
        for (int ks = 0; ks < 2; ++ks) {
            bf16x8 af[4], bfr[4];
#pragma unroll
            for (int i = 0; i < 4; ++i)
                af[i] = *(const bf16x8*)&Al[(wj + i * 16 + l15) * 64 + ks * 32 + q * 8];
#pragma unroll
            for (int i = 0; i < 4; ++i)
                bfr[i] = *(const bf16x8*)&Bl[(wm + i * 16 + l15) * 64 + ks * 32 + q * 8];
#pragma unroll
            for (int i = 0; i < 4; ++i)
#pragma unroll
                for (int jj = 0; jj < 4; ++jj)
                    acc[i][jj] = __builtin_amdgcn_mfma_f32_16x16x32_bf16(af[i], bfr[jj],
                                                                         acc[i][jj], 0, 0, 0);
        }
        __syncthreads();
    }
    // epilogue: D col = lane&15 (channel m), row = q*4+reg (j); fused per-channel sum/sumsq
#pragma unroll
    for (int jj = 0; jj < 4; ++jj) {
        int m = m0 + wm + jj * 16 + l15;
        float bv = bias[m];
        float s = 0.f, s2 = 0.f;
#pragma unroll
        for (int i = 0; i < 4; ++i) {
            int jr = j0 + wj + i * 16 + q * 4;
#pragma unroll
            for (int r = 0; r < 4; ++r) {
                float v = acc[i][jj][r] + bv;
                s += v; s2 += v * v;
                Yb[(size_t)(jr + r) * 256 + m] = f2b(v);
            }
        }
        s += __shfl_xor(s, 16); s += __shfl_xor(s, 32);
        s2 += __shfl_xor(s2, 16); s2 += __shfl_xor(s2, 32);
        if (q == 0) {
            atomicAdd(&stats[m], s);
            atomicAdd(&stats[256 + m], s2);
        }
    }
}

// ---------- BN1+ReLU apply (inline finalize) bf16 -> bf16 ----------
__global__ __launch_bounds__(256) void apply1_kernel(const u16* __restrict__ Y1,
                                                     const float* __restrict__ stats,
                                                     const float* __restrict__ g,
                                                     const float* __restrict__ be,
                                                     u16* __restrict__ X2) {
    size_t i = ((size_t)blockIdx.x * 256 + threadIdx.x) * 4;
    int m = (int)(i & 255);
    float4 sm = *(const float4*)&stats[m];
    float4 sq = *(const float4*)&stats[256 + m];
    float4 gg = *(const float4*)&g[m];
    float4 bb = *(const float4*)&be[m];
    const float inv = 1.f / 32768.f;
    float mean, var, aa[4], ss[4];
    mean = sm.x * inv; var = sq.x * inv - mean * mean; aa[0] = gg.x * rsqrtf(var + 1e-5f); ss[0] = bb.x - mean * aa[0];
    mean = sm.y * inv; var = sq.y * inv - mean * mean; aa[1] = gg.y * rsqrtf(var + 1e-5f); ss[1] = bb.y - mean * aa[1];
    mean = sm.z * inv; var = sq.z * inv - mean * mean; aa[2] = gg.z * rsqrtf(var + 1e-5f); ss[2] = bb.z - mean * aa[2];
    mean = sm.w * inv; var = sq.w * inv - mean * mean; aa[3] = gg.w * rsqrtf(var + 1e-5f); ss[3] = bb.w - mean * aa[3];
    ushort4 v = *(const ushort4*)&Y1[i];
    ushort4 o;
    o.x = f2b(fmaxf(b2f(v.x) * aa[0] + ss[0], 0.f));
    o.y = f2b(fmaxf(b2f(v.y) * aa[1] + ss[1], 0.f));
    o.z = f2b(fmaxf(b2f(v.z) * aa[2] + ss[2], 0.f));
    o.w = f2b(fmaxf(b2f(v.w) * aa[3] + ss[3], 0.f));
    *(ushort4*)&X2[i] = o;
}

// ---------- BN2+ReLU (inline finalize) + transpose [j][o] -> out[b][o][n] ----------
__global__ __launch_bounds__(256) void final_out_kernel(const u16* __restrict__ Y2,
                                                        const float* __restrict__ stats,
                                                        const float* __restrict__ g,
                                                        const float* __restrict__ be,
                                                        float* __restrict__ out) {
    __shared__ float t[64][65];
    int j0 = blockIdx.x * 64, o0 = blockIdx.y * 64;
    int tid = threadIdx.x;
    int c4 = (tid & 15) * 4, rw = tid >> 4;
#pragma unroll
    for (int p = 0; p < 4; ++p) {
        int jl = p * 16 + rw;
        ushort4 v = *(const ushort4*)&Y2[(size_t)(j0 + jl) * 256 + o0 + c4];
        t[jl][c4] = b2f(v.x); t[jl][c4 + 1] = b2f(v.y);
        t[jl][c4 + 2] = b2f(v.z); t[jl][c4 + 3] = b2f(v.w);
    }
    __syncthreads();
    int b = j0 >> 13, n0 = j0 & 8191;
    const float inv = 1.f / 32768.f;
#pragma unroll
    for (int p = 0; p < 4; ++p) {
        int ol = p * 16 + rw;
        int o = o0 + ol;
        float mean = stats[o] * inv;
        float var = stats[256 + o] * inv - mean * mean;
        float a = g[o] * rsqrtf(var + 1e-5f);
        float s = be[o] - mean * a;
        float4 v;
        v.x = fmaxf(t[c4][ol] * a + s, 0.f);
        v.y = fmaxf(t[c4 + 1][ol] * a + s, 0.f);
        v.z = fmaxf(t[c4 + 2][ol] * a + s, 0.f);
        v.w = fmaxf(t[c4 + 3][ol] * a + s, 0.f);
        *(float4*)&out[(size_t)b * 2097152 + (size_t)o * 8192 + n0 + c4] = v;
    }
}

extern "C" void kernel_launch(void* const* d_in, const int* in_sizes, int n_in,
                              void* d_out, int out_size, void* d_ws, size_t ws_size,
                              hipStream_t stream) {
    const float* pos1 = (const float*)d_in[0];
    const float* pos2 = (const float*)d_in[1];
    const float* feature1 = (const float*)d_in[2];
    const float* feature2 = (const float*)d_in[3];
    const float* W1 = (const float*)d_in[4];
    const float* b1 = (const float*)d_in[5];
    const float* g1 = (const float*)d_in[6];
    const float* be1 = (const float*)d_in[7];
    const float* W2 = (const float*)d_in[8];
    const float* b2 = (const float*)d_in[9];
    const float* g2 = (const float*)d_in[10];
    const float* be2 = (const float*)d_in[11];

    char* ws = (char*)d_ws;
    int*   IDX    = (int*)(ws + 0);                 // 393216 B
    float* WGT    = (float*)(ws + 393216);          // 393216 B
    u16*   W1B    = (u16*)(ws + 786432);            // 196608 B
    u16*   W2B    = (u16*)(ws + 983040);            // 131072 B (contiguous after W1B)
    float* STATS  = (float*)(ws + 1114112);         // 4096 B: sum1/sq1/sum2/sq2
    u16*   F2T    = (u16*)(ws + 1118208);           // 4 MiB  [4][2048][256]
    u16*   F1T    = (u16*)(ws + 5312512);           // 8 MiB  [4][8192][128]
    u16*   INTERP = (u16*)(ws + 13701120);          // 16 MiB [32768][256]
    u16*   Y1     = (u16*)(ws + 30478336);          // 16 MiB [32768][256]
    u16*   X2     = (u16*)(ws + 47255552);          // 16 MiB
    u16*   Y2     = (u16*)(ws + 64032768);          // 16 MiB
    float* OUT    = (float*)d_out;

    hipMemsetAsync(STATS, 0, 1024 * sizeof(float), stream);
    prep_kernel<<<NB_CVT + NB_T2 + NB_T1 + NB_NN, 256, 0, stream>>>(
        W1, W2, W1B, feature2, F2T, feature1, F1T, pos1, pos2, IDX, WGT);
    gather_kernel<<<8192, 256, 0, stream>>>(F2T, IDX, WGT, INTERP);
    gemm_kernel<384, true><<<dim3(256, 2), 256, 0, stream>>>(INTERP, F1T, W1B, b1, Y1, STATS);
    apply1_kernel<<<8192, 256, 0, stream>>>(Y1, STATS, g1, be1, X2);
    gemm_kernel<256, false><<<dim3(256, 2), 256, 0, stream>>>(X2, nullptr, W2B, b2, Y2, STATS + 512);
    final_out_kernel<<<dim3(512, 4), 256, 0, stream>>>(Y2, STATS + 512, g2, be2, OUT);
}

// Round 5
// 210.099 us; speedup vs baseline: 1.0512x; 1.0512x over previous
//
#include <hip/hip_runtime.h>
#include <hip/hip_bf16.h>
#include <cstdint>

typedef unsigned short u16;
typedef unsigned int u32;
typedef unsigned long long u64;
typedef __bf16 bf16x8 __attribute__((ext_vector_type(8)));
typedef float f32x4 __attribute__((ext_vector_type(4)));

// ---------- helpers ----------
__device__ __forceinline__ u16 f2b(float f) {          // fp32 -> bf16 RNE
    unsigned int u = __float_as_uint(f);
    u += 0x7fffu + ((u >> 16) & 1u);
    return (u16)(u >> 16);
}
__device__ __forceinline__ float b2f(u16 h) {
    return __uint_as_float(((unsigned int)h) << 16);
}
__device__ __forceinline__ void async_cp16(void* lds, const void* g) {
    __builtin_amdgcn_global_load_lds((const __attribute__((address_space(1))) void*)g,
                                     (__attribute__((address_space(3))) void*)lds, 16, 0, 0);
}
// monotone unsigned mapping of float bits (order-preserving, EXACT)
__device__ __forceinline__ u32 fmono(float f) {
    u32 u = __float_as_uint(f);
    return u ^ (((u32)((int)u >> 31)) | 0x80000000u);
}
__device__ __forceinline__ u64 shfl_xor_u64(u64 v, int mask) {
    u32 lo = (u32)v, hi = (u32)(v >> 32);
    lo = (u32)__shfl_xor((int)lo, mask);
    hi = (u32)__shfl_xor((int)hi, mask);
    return ((u64)hi << 32) | lo;
}
// insert exact key into descending top-3 (keys unique: idx field breaks ties)
__device__ __forceinline__ void ins3(u64 k, u64& k0, u64& k1, u64& k2) {
    bool c0 = k > k0, c1 = k > k1, c2 = k > k2;
    k2 = c1 ? k1 : (c2 ? k : k2);
    k1 = c0 ? k0 : (c1 ? k : k1);
    k0 = c0 ? k : k0;
}
// padded pk index: one float4 pad every 128 entries (bank de-conflict across chunks)
__device__ __forceinline__ int pkix(int i) { return i + (i >> 7); }

// ================= prep kernel: cvt + transpose(f2) + transpose(f1) + three_nn =================
// blocks [0,160): W1/W2 -> bf16        (40960 float4)
// blocks [160,672): feature2 [4][256][2048] -> F2T [4][2048][256] bf16
// blocks [672,1696): feature1 [4][128][8192] -> F1T [4][8192][128] bf16
// blocks [1696,2720): three_nn, 32 queries/block, 2 q/thread, 16 chunks x 128
#define NB_CVT 160
#define NB_T2  512
#define NB_T1  1024
#define NB_NN  1024

__global__ __launch_bounds__(256) void prep_kernel(const float* __restrict__ w1,
                                                   const float* __restrict__ w2,
                                                   u16* __restrict__ wb,
                                                   const float* __restrict__ feature2,
                                                   u16* __restrict__ f2t,
                                                   const float* __restrict__ feature1,
                                                   u16* __restrict__ f1t,
                                                   const float* __restrict__ pos1,
                                                   const float* __restrict__ pos2,
                                                   int* __restrict__ idx_out,
                                                   float* __restrict__ w_out) {
    __shared__ __align__(16) char smem[36096];   // 33024 pk + 3072 warr -> 4 blocks/CU
    int bi = blockIdx.x;
    int tid = threadIdx.x;

    if (bi < NB_CVT) {
        // ---- weight conversion ----
        int i = bi * 256 + tid;
        if (i < 40960) {
            const float* src = (i < 24576) ? w1 : w2;
            int k = (i < 24576) ? i : (i - 24576);
            float4 v = *(const float4*)&src[(size_t)k * 4];
            ushort4 o;
            o.x = f2b(v.x); o.y = f2b(v.y); o.z = f2b(v.z); o.w = f2b(v.w);
            *(ushort4*)&wb[(size_t)i * 4] = o;
        }
        return;
    }
    if (bi < NB_CVT + NB_T2 + NB_T1) {
        // ---- transpose [B][C][S] -> [B][S][C] bf16 ----
        float (*t)[65] = (float (*)[65])smem;
        const float* in; u16* out; int C, S, s0, c0, b;
        if (bi < NB_CVT + NB_T2) {
            int lin = bi - NB_CVT;
            C = 256; S = 2048; in = feature2; out = f2t;
            s0 = (lin & 31) * 64; c0 = ((lin >> 5) & 3) * 64; b = lin >> 7;
        } else {
            int lin = bi - NB_CVT - NB_T2;
            C = 128; S = 8192; in = feature1; out = f1t;
            s0 = (lin & 127) * 64; c0 = ((lin >> 7) & 1) * 64; b = lin >> 8;
        }
        const float* ib = in + (size_t)b * C * S;
        u16* ob = out + (size_t)b * S * C;
        int col = tid & 63, r0 = tid >> 6;
#pragma unroll
        for (int p = 0; p < 16; ++p) {
            int c = p * 4 + r0;
            t[c][col] = ib[(size_t)(c0 + c) * S + s0 + col];
        }
        __syncthreads();
#pragma unroll
        for (int p = 0; p < 16; ++p) {
            int s = p * 4 + r0;
            ob[(size_t)(s0 + s) * C + c0 + col] = f2b(t[col][s]);
        }
        return;
    }

    // ---- three_nn: 32 queries/block (q, q+16 per thread), 16 chunks of 128 cands ----
    // Inner loop: exact fp32 t' = dot - 0.5*|p2|^2, strict > keeps lowest index within chunk.
    // Merges use exact u64 keys (fmono(v)<<32 | 2047-idx): exact value order + low-idx ties.
    float4* pk = (float4*)smem;                          // padded: 2064 float4
    u64* warr = (u64*)(smem + 33024);                    // [4 waves][16 pairs][6 keys]
    int nb = bi - (NB_CVT + NB_T2 + NB_T1);
    int j0 = nb * 32;
    int b = j0 >> 13;
    const float* p2 = pos2 + (size_t)b * 3 * 2048;
    for (int i = tid; i < 2048; i += 256) {
        float x = p2[i], y = p2[2048 + i], z = p2[4096 + i];
        pk[pkix(i)] = make_float4(x, y, z, -0.5f * (x * x + y * y + z * z));
    }
    __syncthreads();
    int p = tid & 15, ck = tid >> 4;          // ck 0..15
    int wv = tid >> 6, lane = tid & 63;
    int na = (j0 & 8191) + p, nbq = na + 16;
    const float* p1 = pos1 + (size_t)b * 3 * 8192;
    float xa = p1[na], ya = p1[8192 + na], za = p1[16384 + na];
    float xb = p1[nbq], yb = p1[8192 + nbq], zb = p1[16384 + nbq];

    float ga0 = -3.4e38f, ga1 = -3.4e38f, ga2 = -3.4e38f;
    float gb0 = -3.4e38f, gb1 = -3.4e38f, gb2 = -3.4e38f;
    int ia0 = 0, ia1 = 0, ia2 = 0, ib0 = 0, ib1 = 0, ib2 = 0;
    int sb = ck * 128;
    const float4* pc = pk + pkix(sb);        // within a chunk: contiguous (no pad crossing)
#pragma unroll 4
    for (int it = 0; it < 128; ++it) {
        float4 cd = pc[it];
        int s = sb + it;
        float ta = fmaf(xa, cd.x, fmaf(ya, cd.y, fmaf(za, cd.z, cd.w)));
        float tb = fmaf(xb, cd.x, fmaf(yb, cd.y, fmaf(zb, cd.z, cd.w)));
        bool a0 = ta > ga0, a1 = ta > ga1, a2 = ta > ga2;
        ga2 = a1 ? ga1 : (a2 ? ta : ga2);
        ia2 = a1 ? ia1 : (a2 ? s : ia2);
        ga1 = a0 ? ga0 : (a1 ? ta : ga1);
        ia1 = a0 ? ia0 : (a1 ? s : ia1);
        ga0 = a0 ? ta : ga0;
        ia0 = a0 ? s : ia0;
        bool b0c = tb > gb0, b1c = tb > gb1, b2c = tb > gb2;
        gb2 = b1c ? gb1 : (b2c ? tb : gb2);
        ib2 = b1c ? ib1 : (b2c ? s : ib2);
        gb1 = b0c ? gb0 : (b1c ? tb : gb1);
        ib1 = b0c ? ib0 : (b1c ? s : ib1);
        gb0 = b0c ? tb : gb0;
        ib0 = b0c ? s : ib0;
    }
    // pack exact keys
    u64 a0k = ((u64)fmono(ga0) << 32) | (u64)(2047 - ia0);
    u64 a1k = ((u64)fmono(ga1) << 32) | (u64)(2047 - ia1);
    u64 a2k = ((u64)fmono(ga2) << 32) | (u64)(2047 - ia2);
    u64 b0k = ((u64)fmono(gb0) << 32) | (u64)(2047 - ib0);
    u64 b1k = ((u64)fmono(gb1) << 32) | (u64)(2047 - ib1);
    u64 b2k = ((u64)fmono(gb2) << 32) | (u64)(2047 - ib2);
    // in-wave merge across the 4 chunk-groups (lanes p+16g)
#pragma unroll
    for (int mask = 16; mask <= 32; mask <<= 1) {
        u64 pa0 = shfl_xor_u64(a0k, mask), pa1 = shfl_xor_u64(a1k, mask), pa2 = shfl_xor_u64(a2k, mask);
        u64 pb0 = shfl_xor_u64(b0k, mask), pb1 = shfl_xor_u64(b1k, mask), pb2 = shfl_xor_u64(b2k, mask);
        ins3(pa0, a0k, a1k, a2k); ins3(pa1, a0k, a1k, a2k); ins3(pa2, a0k, a1k, a2k);
        ins3(pb0, b0k, b1k, b2k); ins3(pb1, b0k, b1k, b2k); ins3(pb2, b0k, b1k, b2k);
    }
    if (lane < 16) {
        u64* wr = &warr[(wv * 16 + p) * 6];
        wr[0] = a0k; wr[1] = a1k; wr[2] = a2k;
        wr[3] = b0k; wr[4] = b1k; wr[5] = b2k;
    }
    __syncthreads();
    if (tid < 32) {
        int q = tid;
        int pp = q & 15, off = (q < 16) ? 0 : 3;
        const u64* w0 = &warr[pp * 6];
        u64 k0 = w0[off], k1 = w0[off + 1], k2 = w0[off + 2];
#pragma unroll
        for (int w = 1; w < 4; ++w) {
            const u64* wr = &warr[(w * 16 + pp) * 6];
            ins3(wr[off], k0, k1, k2);
            ins3(wr[off + 1], k0, k1, k2);
            ins3(wr[off + 2], k0, k1, k2);
        }
        int s0 = 2047 - (int)(k0 & 0xFFFFFFFFu);
        int s1 = 2047 - (int)(k1 & 0xFFFFFFFFu);
        int s2 = 2047 - (int)(k2 & 0xFFFFFFFFu);
        int j = j0 + q;
        int n = j & 8191;
        float x1 = p1[n], y1 = p1[8192 + n], z1 = p1[16384 + n];
        float n1 = x1 * x1 + y1 * y1 + z1 * z1;
        float4 c0v = pk[pkix(s0)], c1v = pk[pkix(s1)], c2v = pk[pkix(s2)];
        float t0 = fmaf(x1, c0v.x, fmaf(y1, c0v.y, fmaf(z1, c0v.z, c0v.w)));
        float t1 = fmaf(x1, c1v.x, fmaf(y1, c1v.y, fmaf(z1, c1v.z, c1v.w)));
        float t2 = fmaf(x1, c2v.x, fmaf(y1, c2v.y, fmaf(z1, c2v.z, c2v.w)));
        float d0 = fmaxf(fmaf(-2.f, t0, n1), 1e-10f);
        float d1 = fmaxf(fmaf(-2.f, t1, n1), 1e-10f);
        float d2 = fmaxf(fmaf(-2.f, t2, n1), 1e-10f);
        float w0v = 1.f / d0, w1v = 1.f / d1, w2v = 1.f / d2;
        float inv = 1.f / (w0v + w1v + w2v);
        idx_out[j * 3] = s0; idx_out[j * 3 + 1] = s1; idx_out[j * 3 + 2] = s2;
        w_out[j * 3] = w0v * inv; w_out[j * 3 + 1] = w1v * inv; w_out[j * 3 + 2] = w2v * inv;
    }
}

// ---------- gather + interpolate -> INTERP [32768][256] bf16 ----------
__global__ __launch_bounds__(256) void gather_kernel(const u16* __restrict__ f2t,
                                                     const int* __restrict__ idx,
                                                     const float* __restrict__ wgt,
                                                     u16* __restrict__ interp) {
    int wv = threadIdx.x >> 6, lane = threadIdx.x & 63;
    int j = blockIdx.x * 4 + wv;
    int b = j >> 13;
    int i0 = idx[j * 3], i1 = idx[j * 3 + 1], i2 = idx[j * 3 + 2];
    float w0 = wgt[j * 3], w1 = wgt[j * 3 + 1], w2 = wgt[j * 3 + 2];
    const u16* r0 = f2t + ((size_t)(b * 2048 + i0)) * 256;
    const u16* r1 = f2t + ((size_t)(b * 2048 + i1)) * 256;
    const u16* r2 = f2t + ((size_t)(b * 2048 + i2)) * 256;
    int c = lane * 4;
    ushort4 v0 = *(const ushort4*)(r0 + c);
    ushort4 v1 = *(const ushort4*)(r1 + c);
    ushort4 v2 = *(const ushort4*)(r2 + c);
    ushort4 o;
    o.x = f2b(w0 * b2f(v0.x) + w1 * b2f(v1.x) + w2 * b2f(v2.x));
    o.y = f2b(w0 * b2f(v0.y) + w1 * b2f(v1.y) + w2 * b2f(v2.y));
    o.z = f2b(w0 * b2f(v0.z) + w1 * b2f(v1.z) + w2 * b2f(v2.z));
    o.w = f2b(w0 * b2f(v0.w) + w1 * b2f(v1.w) + w2 * b2f(v2.w));
    *(ushort4*)(interp + (size_t)j * 256 + c) = o;
}

// ---------- GEMM: Yb[j][m] = bf16(sum_k A[j][k]*Bw[m][k] + bias[m]), fused BN stats ----------
// SPLIT: A = [A1 (k<256, stride 256) | A2 (k>=256, stride 128)], KT = total K
template <int KT, bool SPLIT>
__global__ __launch_bounds__(256, 2) void gemm_kernel(const u16* __restrict__ A1,
                                                      const u16* __restrict__ A2,
                                                      const u16* __restrict__ Bw,
                                                      const float* __restrict__ bias,
                                                      u16* __restrict__ Yb,
                                                      float* __restrict__ stats) {
    __shared__ u16 Al[128 * 64];
    __shared__ u16 Bl[128 * 64];
    int tid = threadIdx.x;
    int lane = tid & 63, wv = tid >> 6;
    int j0 = blockIdx.x * 128, m0 = blockIdx.y * 128;
    int l15 = lane & 15, q = lane >> 4;
    int wj = (wv >> 1) * 64, wm = (wv & 1) * 64;
    f32x4 acc[4][4];
#pragma unroll
    for (int i = 0; i < 4; ++i)
#pragma unroll
        for (int jj = 0; jj < 4; ++jj) acc[i][jj] = (f32x4){0.f, 0.f, 0.f, 0.f};

    int rbase = wv * 32;
    int lrow = lane >> 3, lchunk = lane & 7;
    const u16* Bg = Bw + (size_t)m0 * KT;

    for (int k0 = 0; k0 < KT; k0 += 64) {
        const u16* src; int stride;
        if (!SPLIT || k0 < 256) { src = A1 + (size_t)j0 * 256 + k0; stride = 256; }
        else                    { src = A2 + (size_t)j0 * 128 + (k0 - 256); stride = 128; }
#pragma unroll
        for (int qq = 0; qq < 4; ++qq) {
            int row = rbase + qq * 8;   // wave-uniform LDS base; HW adds lane*16B
            async_cp16(&Al[row * 64], src + (size_t)(row + lrow) * stride + lchunk * 8);
            async_cp16(&Bl[row * 64], Bg + (size_t)(row + lrow) * KT + k0 + lchunk * 8);
        }
        __syncthreads();
#pragma unroll
        for (int ks = 0; ks < 2; ++ks) {
            bf16x8 af[4], bfr[4];
#pragma unroll
            for (int i = 0; i < 4; ++i)
                af[i] = *(const bf16x8*)&Al[(wj + i * 16 + l15) * 64 + ks * 32 + q * 8];
#pragma unroll
            for (int i = 0; i < 4; ++i)
                bfr[i] = *(const bf16x8*)&Bl[(wm + i * 16 + l15) * 64 + ks * 32 + q * 8];
#pragma unroll
            for (int i = 0; i < 4; ++i)
#pragma unroll
                for (int jj = 0; jj < 4; ++jj)
                    acc[i][jj] = __builtin_amdgcn_mfma_f32_16x16x32_bf16(af[i], bfr[jj],
                                                                         acc[i][jj], 0, 0, 0);
        }
        __syncthreads();
    }
    // epilogue: D col = lane&15 (channel m), row = q*4+reg (j); fused per-channel sum/sumsq
#pragma unroll
    for (int jj = 0; jj < 4; ++jj) {
        int m = m0 + wm + jj * 16 + l15;
        float bv = bias[m];
        float s = 0.f, s2 = 0.f;
#pragma unroll
        for (int i = 0; i < 4; ++i) {
            int jr = j0 + wj + i * 16 + q * 4;
#pragma unroll
            for (int r = 0; r < 4; ++r) {
                float v = acc[i][jj][r] + bv;
                s += v; s2 += v * v;
                Yb[(size_t)(jr + r) * 256 + m] = f2b(v);
            }
        }
        s += __shfl_xor(s, 16); s += __shfl_xor(s, 32);
        s2 += __shfl_xor(s2, 16); s2 += __shfl_xor(s2, 32);
        if (q == 0) {
            atomicAdd(&stats[m], s);
            atomicAdd(&stats[256 + m], s2);
        }
    }
}

// ---------- BN1+ReLU apply (inline finalize) bf16 -> bf16 ----------
__global__ __launch_bounds__(256) void apply1_kernel(const u16* __restrict__ Y1,
                                                     const float* __restrict__ stats,
                                                     const float* __restrict__ g,
                                                     const float* __restrict__ be,
                                                     u16* __restrict__ X2) {
    size_t i = ((size_t)blockIdx.x * 256 + threadIdx.x) * 4;
    int m = (int)(i & 255);
    float4 sm = *(const float4*)&stats[m];
    float4 sq = *(const float4*)&stats[256 + m];
    float4 gg = *(const float4*)&g[m];
    float4 bb = *(const float4*)&be[m];
    const float inv = 1.f / 32768.f;
    float mean, var, aa[4], ss[4];
    mean = sm.x * inv; var = sq.x * inv - mean * mean; aa[0] = gg.x * rsqrtf(var + 1e-5f); ss[0] = bb.x - mean * aa[0];
    mean = sm.y * inv; var = sq.y * inv - mean * mean; aa[1] = gg.y * rsqrtf(var + 1e-5f); ss[1] = bb.y - mean * aa[1];
    mean = sm.z * inv; var = sq.z * inv - mean * mean; aa[2] = gg.z * rsqrtf(var + 1e-5f); ss[2] = bb.z - mean * aa[2];
    mean = sm.w * inv; var = sq.w * inv - mean * mean; aa[3] = gg.w * rsqrtf(var + 1e-5f); ss[3] = bb.w - mean * aa[3];
    ushort4 v = *(const ushort4*)&Y1[i];
    ushort4 o;
    o.x = f2b(fmaxf(b2f(v.x) * aa[0] + ss[0], 0.f));
    o.y = f2b(fmaxf(b2f(v.y) * aa[1] + ss[1], 0.f));
    o.z = f2b(fmaxf(b2f(v.z) * aa[2] + ss[2], 0.f));
    o.w = f2b(fmaxf(b2f(v.w) * aa[3] + ss[3], 0.f));
    *(ushort4*)&X2[i] = o;
}

// ---------- BN2+ReLU (inline finalize) + transpose [j][o] -> out[b][o][n] ----------
__global__ __launch_bounds__(256) void final_out_kernel(const u16* __restrict__ Y2,
                                                        const float* __restrict__ stats,
                                                        const float* __restrict__ g,
                                                        const float* __restrict__ be,
                                                        float* __restrict__ out) {
    __shared__ float t[64][65];
    int j0 = blockIdx.x * 64, o0 = blockIdx.y * 64;
    int tid = threadIdx.x;
    int c4 = (tid & 15) * 4, rw = tid >> 4;
#pragma unroll
    for (int p = 0; p < 4; ++p) {
        int jl = p * 16 + rw;
        ushort4 v = *(const ushort4*)&Y2[(size_t)(j0 + jl) * 256 + o0 + c4];
        t[jl][c4] = b2f(v.x); t[jl][c4 + 1] = b2f(v.y);
        t[jl][c4 + 2] = b2f(v.z); t[jl][c4 + 3] = b2f(v.w);
    }
    __syncthreads();
    int b = j0 >> 13, n0 = j0 & 8191;
    const float inv = 1.f / 32768.f;
#pragma unroll
    for (int p = 0; p < 4; ++p) {
        int ol = p * 16 + rw;
        int o = o0 + ol;
        float mean = stats[o] * inv;
        float var = stats[256 + o] * inv - mean * mean;
        float a = g[o] * rsqrtf(var + 1e-5f);
        float s = be[o] - mean * a;
        float4 v;
        v.x = fmaxf(t[c4][ol] * a + s, 0.f);
        v.y = fmaxf(t[c4 + 1][ol] * a + s, 0.f);
        v.z = fmaxf(t[c4 + 2][ol] * a + s, 0.f);
        v.w = fmaxf(t[c4 + 3][ol] * a + s, 0.f);
        *(float4*)&out[(size_t)b * 2097152 + (size_t)o * 8192 + n0 + c4] = v;
    }
}

extern "C" void kernel_launch(void* const* d_in, const int* in_sizes, int n_in,
                              void* d_out, int out_size, void* d_ws, size_t ws_size,
                              hipStream_t stream) {
    const float* pos1 = (const float*)d_in[0];
    const float* pos2 = (const float*)d_in[1];
    const float* feature1 = (const float*)d_in[2];
    const float* feature2 = (const float*)d_in[3];
    const float* W1 = (const float*)d_in[4];
    const float* b1 = (const float*)d_in[5];
    const float* g1 = (const float*)d_in[6];
    const float* be1 = (const float*)d_in[7];
    const float* W2 = (const float*)d_in[8];
    const float* b2 = (const float*)d_in[9];
    const float* g2 = (const float*)d_in[10];
    const float* be2 = (const float*)d_in[11];

    char* ws = (char*)d_ws;
    int*   IDX    = (int*)(ws + 0);                 // 393216 B
    float* WGT    = (float*)(ws + 393216);          // 393216 B
    u16*   W1B    = (u16*)(ws + 786432);            // 196608 B
    u16*   W2B    = (u16*)(ws + 983040);            // 131072 B (contiguous after W1B)
    float* STATS  = (float*)(ws + 1114112);         // 4096 B: sum1/sq1/sum2/sq2
    u16*   F2T    = (u16*)(ws + 1118208);           // 4 MiB  [4][2048][256]
    u16*   F1T    = (u16*)(ws + 5312512);           // 8 MiB  [4][8192][128]
    u16*   INTERP = (u16*)(ws + 13701120);          // 16 MiB [32768][256]
    u16*   Y1     = (u16*)(ws + 30478336);          // 16 MiB [32768][256]
    u16*   X2     = (u16*)(ws + 47255552);          // 16 MiB
    u16*   Y2     = (u16*)(ws + 64032768);          // 16 MiB
    float* OUT    = (float*)d_out;

    hipMemsetAsync(STATS, 0, 1024 * sizeof(float), stream);
    prep_kernel<<<NB_CVT + NB_T2 + NB_T1 + NB_NN, 256, 0, stream>>>(
        W1, W2, W1B, feature2, F2T, feature1, F1T, pos1, pos2, IDX, WGT);
    gather_kernel<<<8192, 256, 0, stream>>>(F2T, IDX, WGT, INTERP);
    gemm_kernel<384, true><<<dim3(256, 2), 256, 0, stream>>>(INTERP, F1T, W1B, b1, Y1, STATS);
    apply1_kernel<<<8192, 256, 0, stream>>>(Y1, STATS, g1, be1, X2);
    gemm_kernel<256, false><<<dim3(256, 2), 256, 0, stream>>>(X2, nullptr, W2B, b2, Y2, STATS + 512);
    final_out_kernel<<<dim3(512, 4), 256, 0, stream>>>(Y2, STATS + 512, g2, be2, OUT);
}

// Round 6
// 208.987 us; speedup vs baseline: 1.0568x; 1.0053x over previous
//
#include <hip/hip_runtime.h>
#include <hip/hip_bf16.h>
#include <cstdint>

typedef unsigned short u16;
typedef unsigned int u32;
typedef unsigned long long u64;
typedef __bf16 bf16x8 __attribute__((ext_vector_type(8)));
typedef float f32x4 __attribute__((ext_vector_type(4)));

// ---------- helpers ----------
__device__ __forceinline__ u16 f2b(float f) {          // fp32 -> bf16 RNE
    unsigned int u = __float_as_uint(f);
    u += 0x7fffu + ((u >> 16) & 1u);
    return (u16)(u >> 16);
}
__device__ __forceinline__ float b2f(u16 h) {
    return __uint_as_float(((unsigned int)h) << 16);
}
__device__ __forceinline__ void async_cp16(void* lds, const void* g) {
    __builtin_amdgcn_global_load_lds((const __attribute__((address_space(1))) void*)g,
                                     (__attribute__((address_space(3))) void*)lds, 16, 0, 0);
}
// monotone unsigned mapping of float bits (order-preserving, EXACT)
__device__ __forceinline__ u32 fmono(float f) {
    u32 u = __float_as_uint(f);
    return u ^ (((u32)((int)u >> 31)) | 0x80000000u);
}
__device__ __forceinline__ u64 shfl_xor_u64(u64 v, int mask) {
    u32 lo = (u32)v, hi = (u32)(v >> 32);
    lo = (u32)__shfl_xor((int)lo, mask);
    hi = (u32)__shfl_xor((int)hi, mask);
    return ((u64)hi << 32) | lo;
}
// insert exact key into descending top-3 (keys unique: idx field breaks ties)
__device__ __forceinline__ void ins3(u64 k, u64& k0, u64& k1, u64& k2) {
    bool c0 = k > k0, c1 = k > k1, c2 = k > k2;
    k2 = c1 ? k1 : (c2 ? k : k2);
    k1 = c0 ? k0 : (c1 ? k : k1);
    k0 = c0 ? k : k0;
}
// padded pk index: one float4 pad every 128 entries (bank de-conflict across chunk groups)
__device__ __forceinline__ int pkix(int i) { return i + (i >> 7); }

// ================= prep kernel: three_nn FIRST, then cvt + transposes =================
// blocks [0,1024): three_nn, 32 queries/block, 2 q/thread, 2 S-halves of 1024
// blocks [1024,1184): W1/W2 -> bf16 (40960 float4)
// blocks [1184,1696): feature2 [4][256][2048] -> F2T [4][2048][256] bf16
// blocks [1696,2720): feature1 [4][128][8192] -> F1T [4][8192][128] bf16
#define NB_NN  1024
#define NB_CVT 160
#define NB_T2  512
#define NB_T1  1024

__global__ __launch_bounds__(256, 8) void prep_kernel(const float* __restrict__ w1,
                                                      const float* __restrict__ w2,
                                                      u16* __restrict__ wb,
                                                      const float* __restrict__ feature2,
                                                      u16* __restrict__ f2t,
                                                      const float* __restrict__ feature1,
                                                      u16* __restrict__ f1t,
                                                      const float* __restrict__ pos1,
                                                      const float* __restrict__ pos2,
                                                      int* __restrict__ idx_out,
                                                      float* __restrict__ w_out) {
    __shared__ __align__(16) char smem[19712];   // 16512 pk-half + 3072 warr -> 8 blocks/CU
    int bi = blockIdx.x;
    int tid = threadIdx.x;

    if (bi >= NB_NN) {
        int ci = bi - NB_NN;
        if (ci < NB_CVT) {
            // ---- weight conversion ----
            int i = ci * 256 + tid;
            if (i < 40960) {
                const float* src = (i < 24576) ? w1 : w2;
                int k = (i < 24576) ? i : (i - 24576);
                float4 v = *(const float4*)&src[(size_t)k * 4];
                ushort4 o;
                o.x = f2b(v.x); o.y = f2b(v.y); o.z = f2b(v.z); o.w = f2b(v.w);
                *(ushort4*)&wb[(size_t)i * 4] = o;
            }
            return;
        }
        // ---- transpose [B][C][S] -> [B][S][C] bf16 ----
        float (*t)[65] = (float (*)[65])smem;    // 16640 B <= 19712
        const float* in; u16* out; int C, S, s0, c0, b;
        if (ci < NB_CVT + NB_T2) {
            int lin = ci - NB_CVT;
            C = 256; S = 2048; in = feature2; out = f2t;
            s0 = (lin & 31) * 64; c0 = ((lin >> 5) & 3) * 64; b = lin >> 7;
        } else {
            int lin = ci - NB_CVT - NB_T2;
            C = 128; S = 8192; in = feature1; out = f1t;
            s0 = (lin & 127) * 64; c0 = ((lin >> 7) & 1) * 64; b = lin >> 8;
        }
        const float* ib = in + (size_t)b * C * S;
        u16* ob = out + (size_t)b * S * C;
        int col = tid & 63, r0 = tid >> 6;
#pragma unroll
        for (int p = 0; p < 16; ++p) {
            int c = p * 4 + r0;
            t[c][col] = ib[(size_t)(c0 + c) * S + s0 + col];
        }
        __syncthreads();
#pragma unroll
        for (int p = 0; p < 16; ++p) {
            int s = p * 4 + r0;
            ob[(size_t)(s0 + s) * C + c0 + col] = f2b(t[col][s]);
        }
        return;
    }

    // ---- three_nn: 32 queries/block (q, q+16 per thread), 2 halves x 16 chunks x 64 ----
    // Exact fp32 t' = dot - 0.5*|p2|^2; strict > keeps lowest index within a chunk;
    // all merges via exact u64 keys (fmono(v)<<32 | 2047-idx): value order + low-idx ties.
    float4* pk = (float4*)smem;                          // padded: 1032 float4 = 16512 B
    u64* warr = (u64*)(smem + 16512);                    // [4 waves][16 pairs][6 keys]
    int j0 = bi * 32;
    int b = j0 >> 13;
    const float* p2 = pos2 + (size_t)b * 3 * 2048;
    int p = tid & 15, ck = tid >> 4;          // ck 0..15
    int wv = tid >> 6, lane = tid & 63;
    int na = (j0 & 8191) + p, nbq = na + 16;
    const float* p1 = pos1 + (size_t)b * 3 * 8192;
    float xa = p1[na], ya = p1[8192 + na], za = p1[16384 + na];
    float xb = p1[nbq], yb = p1[8192 + nbq], zb = p1[16384 + nbq];

    u64 a0k = 0, a1k = 0, a2k = 0, b0k = 0, b1k = 0, b2k = 0;

    for (int half = 0; half < 2; ++half) {
        int hbase = half * 1024;
        // stage this half of candidates
        for (int i = tid; i < 1024; i += 256) {
            int s = hbase + i;
            float x = p2[s], y = p2[2048 + s], z = p2[4096 + s];
            pk[pkix(i)] = make_float4(x, y, z, -0.5f * (x * x + y * y + z * z));
        }
        __syncthreads();

        float ga0 = -3.4e38f, ga1 = -3.4e38f, ga2 = -3.4e38f;
        float gb0 = -3.4e38f, gb1 = -3.4e38f, gb2 = -3.4e38f;
        int ia0 = 0, ia1 = 0, ia2 = 0, ib0 = 0, ib1 = 0, ib2 = 0;
        int sb = ck * 64;
        const float4* pc = pk + pkix(sb);    // 64-chunks never cross a 128-pad boundary
#pragma unroll 4
        for (int it = 0; it < 64; ++it) {
            float4 cd = pc[it];
            int s = sb + it;
            float ta = fmaf(xa, cd.x, fmaf(ya, cd.y, fmaf(za, cd.z, cd.w)));
            float tb = fmaf(xb, cd.x, fmaf(yb, cd.y, fmaf(zb, cd.z, cd.w)));
            bool a0 = ta > ga0, a1 = ta > ga1, a2 = ta > ga2;
            ga2 = a1 ? ga1 : (a2 ? ta : ga2);
            ia2 = a1 ? ia1 : (a2 ? s : ia2);
            ga1 = a0 ? ga0 : (a1 ? ta : ga1);
            ia1 = a0 ? ia0 : (a1 ? s : ia1);
            ga0 = a0 ? ta : ga0;
            ia0 = a0 ? s : ia0;
            bool b0c = tb > gb0, b1c = tb > gb1, b2c = tb > gb2;
            gb2 = b1c ? gb1 : (b2c ? tb : gb2);
            ib2 = b1c ? ib1 : (b2c ? s : ib2);
            gb1 = b0c ? gb0 : (b1c ? tb : gb1);
            ib1 = b0c ? ib0 : (b1c ? s : ib1);
            gb0 = b0c ? tb : gb0;
            ib0 = b0c ? s : ib0;
        }
        __syncthreads();   // all reads done before next half restages

        // fold this half's results into the running exact-key top-3
        int gi0 = hbase + ia0, gi1 = hbase + ia1, gi2 = hbase + ia2;
        int gj0 = hbase + ib0, gj1 = hbase + ib1, gj2 = hbase + ib2;
        ins3(((u64)fmono(ga0) << 32) | (u64)(2047 - gi0), a0k, a1k, a2k);
        ins3(((u64)fmono(ga1) << 32) | (u64)(2047 - gi1), a0k, a1k, a2k);
        ins3(((u64)fmono(ga2) << 32) | (u64)(2047 - gi2), a0k, a1k, a2k);
        ins3(((u64)fmono(gb0) << 32) | (u64)(2047 - gj0), b0k, b1k, b2k);
        ins3(((u64)fmono(gb1) << 32) | (u64)(2047 - gj1), b0k, b1k, b2k);
        ins3(((u64)fmono(gb2) << 32) | (u64)(2047 - gj2), b0k, b1k, b2k);
    }

    // in-wave merge across the 4 chunk-groups (lanes p+16g)
#pragma unroll
    for (int mask = 16; mask <= 32; mask <<= 1) {
        u64 pa0 = shfl_xor_u64(a0k, mask), pa1 = shfl_xor_u64(a1k, mask), pa2 = shfl_xor_u64(a2k, mask);
        u64 pb0 = shfl_xor_u64(b0k, mask), pb1 = shfl_xor_u64(b1k, mask), pb2 = shfl_xor_u64(b2k, mask);
        ins3(pa0, a0k, a1k, a2k); ins3(pa1, a0k, a1k, a2k); ins3(pa2, a0k, a1k, a2k);
        ins3(pb0, b0k, b1k, b2k); ins3(pb1, b0k, b1k, b2k); ins3(pb2, b0k, b1k, b2k);
    }
    if (lane < 16) {
        u64* wr = &warr[(wv * 16 + p) * 6];
        wr[0] = a0k; wr[1] = a1k; wr[2] = a2k;
        wr[3] = b0k; wr[4] = b1k; wr[5] = b2k;
    }
    __syncthreads();
    if (tid < 32) {
        int q = tid;
        int pp = q & 15, off = (q < 16) ? 0 : 3;
        const u64* w0 = &warr[pp * 6];
        u64 k0 = w0[off], k1 = w0[off + 1], k2 = w0[off + 2];
#pragma unroll
        for (int w = 1; w < 4; ++w) {
            const u64* wr = &warr[(w * 16 + pp) * 6];
            ins3(wr[off], k0, k1, k2);
            ins3(wr[off + 1], k0, k1, k2);
            ins3(wr[off + 2], k0, k1, k2);
        }
        int s0 = 2047 - (int)(k0 & 0xFFFFFFFFu);
        int s1 = 2047 - (int)(k1 & 0xFFFFFFFFu);
        int s2 = 2047 - (int)(k2 & 0xFFFFFFFFu);
        int j = j0 + q;
        int n = j & 8191;
        float x1 = p1[n], y1 = p1[8192 + n], z1 = p1[16384 + n];
        float n1 = x1 * x1 + y1 * y1 + z1 * z1;
        // exact weights recomputed from global pos2 (L2-hot; 32 threads only)
        float X0 = p2[s0], Y0 = p2[2048 + s0], Z0 = p2[4096 + s0];
        float X1 = p2[s1], Y1v = p2[2048 + s1], Z1 = p2[4096 + s1];
        float X2 = p2[s2], Y2v = p2[2048 + s2], Z2 = p2[4096 + s2];
        float t0 = x1 * X0 + y1 * Y0 + z1 * Z0 - 0.5f * (X0 * X0 + Y0 * Y0 + Z0 * Z0);
        float t1 = x1 * X1 + y1 * Y1v + z1 * Z1 - 0.5f * (X1 * X1 + Y1v * Y1v + Z1 * Z1);
        float t2 = x1 * X2 + y1 * Y2v + z1 * Z2 - 0.5f * (X2 * X2 + Y2v * Y2v + Z2 * Z2);
        float d0 = fmaxf(fmaf(-2.f, t0, n1), 1e-10f);
        float d1 = fmaxf(fmaf(-2.f, t1, n1), 1e-10f);
        float d2 = fmaxf(fmaf(-2.f, t2, n1), 1e-10f);
        float w0v = 1.f / d0, w1v = 1.f / d1, w2v = 1.f / d2;
        float inv = 1.f / (w0v + w1v + w2v);
        idx_out[j * 3] = s0; idx_out[j * 3 + 1] = s1; idx_out[j * 3 + 2] = s2;
        w_out[j * 3] = w0v * inv; w_out[j * 3 + 1] = w1v * inv; w_out[j * 3 + 2] = w2v * inv;
    }
}

// ---------- gather + interpolate -> INTERP [32768][256] bf16 ----------
__global__ __launch_bounds__(256) void gather_kernel(const u16* __restrict__ f2t,
                                                     const int* __restrict__ idx,
                                                     const float* __restrict__ wgt,
                                                     u16* __restrict__ interp) {
    int wv = threadIdx.x >> 6, lane = threadIdx.x & 63;
    int j = blockIdx.x * 4 + wv;
    int b = j >> 13;
    int i0 = idx[j * 3], i1 = idx[j * 3 + 1], i2 = idx[j * 3 + 2];
    float w0 = wgt[j * 3], w1 = wgt[j * 3 + 1], w2 = wgt[j * 3 + 2];
    const u16* r0 = f2t + ((size_t)(b * 2048 + i0)) * 256;
    const u16* r1 = f2t + ((size_t)(b * 2048 + i1)) * 256;
    const u16* r2 = f2t + ((size_t)(b * 2048 + i2)) * 256;
    int c = lane * 4;
    ushort4 v0 = *(const ushort4*)(r0 + c);
    ushort4 v1 = *(const ushort4*)(r1 + c);
    ushort4 v2 = *(const ushort4*)(r2 + c);
    ushort4 o;
    o.x = f2b(w0 * b2f(v0.x) + w1 * b2f(v1.x) + w2 * b2f(v2.x));
    o.y = f2b(w0 * b2f(v0.y) + w1 * b2f(v1.y) + w2 * b2f(v2.y));
    o.z = f2b(w0 * b2f(v0.z) + w1 * b2f(v1.z) + w2 * b2f(v2.z));
    o.w = f2b(w0 * b2f(v0.w) + w1 * b2f(v1.w) + w2 * b2f(v2.w));
    *(ushort4*)(interp + (size_t)j * 256 + c) = o;
}

// ---------- GEMM: Yb[j][m] = bf16(sum_k A[j][k]*Bw[m][k] + bias[m]), fused BN stats ----------
// SPLIT: A = [A1 (k<256, stride 256) | A2 (k>=256, stride 128)], KT = total K
template <int KT, bool SPLIT>
__global__ __launch_bounds__(256, 2) void gemm_kernel(const u16* __restrict__ A1,
                                                      const u16* __restrict__ A2,
                                                      const u16* __restrict__ Bw,
                                                      const float* __restrict__ bias,
                                                      u16* __restrict__ Yb,
                                                      float* __restrict__ stats) {
    __shared__ u16 Al[128 * 64];
    __shared__ u16 Bl[128 * 64];
    int tid = threadIdx.x;
    int lane = tid & 63, wv = tid >> 6;
    int j0 = blockIdx.x * 128, m0 = blockIdx.y * 128;
    int l15 = lane & 15, q = lane >> 4;
    int wj = (wv >> 1) * 64, wm = (wv & 1) * 64;
    f32x4 acc[4][4];
#pragma unroll
    for (int i = 0; i < 4; ++i)
#pragma unroll
        for (int jj = 0; jj < 4; ++jj) acc[i][jj] = (f32x4){0.f, 0.f, 0.f, 0.f};

    int rbase = wv * 32;
    int lrow = lane >> 3, lchunk = lane & 7;
    const u16* Bg = Bw + (size_t)m0 * KT;

    for (int k0 = 0; k0 < KT; k0 += 64) {
        const u16* src; int stride;
        if (!SPLIT || k0 < 256) { src = A1 + (size_t)j0 * 256 + k0; stride = 256; }
        else                    { src = A2 + (size_t)j0 * 128 + (k0 - 256); stride = 128; }
#pragma unroll
        for (int qq = 0; qq < 4; ++qq) {
            int row = rbase + qq * 8;   // wave-uniform LDS base; HW adds lane*16B
            async_cp16(&Al[row * 64], src + (size_t)(row + lrow) * stride + lchunk * 8);
            async_cp16(&Bl[row * 64], Bg + (size_t)(row + lrow) * KT + k0 + lchunk * 8);
        }
        __syncthreads();
#pragma unroll
        for (int ks = 0; ks < 2; ++ks) {
            bf16x8 af[4], bfr[4];
#pragma unroll
            for (int i = 0; i < 4; ++i)
                af[i] = *(const bf16x8*)&Al[(wj + i * 16 + l15) * 64 + ks * 32 + q * 8];
#pragma unroll
            for (int i = 0; i < 4; ++i)
                bfr[i] = *(const bf16x8*)&Bl[(wm + i * 16 + l15) * 64 + ks * 32 + q * 8];
#pragma unroll
            for (int i = 0; i < 4; ++i)
#pragma unroll
                for (int jj = 0; jj < 4; ++jj)
                    acc[i][jj] = __builtin_amdgcn_mfma_f32_16x16x32_bf16(af[i], bfr[jj],
                                                                         acc[i][jj], 0, 0, 0);
        }
        __syncthreads();
    }
    // epilogue: D col = lane&15 (channel m), row = q*4+reg (j); fused per-channel sum/sumsq
#pragma unroll
    for (int jj = 0; jj < 4; ++jj) {
        int m = m0 + wm + jj * 16 + l15;
        float bv = bias[m];
        float s = 0.f, s2 = 0.f;
#pragma unroll
        for (int i = 0; i < 4; ++i) {
            int jr = j0 + wj + i * 16 + q * 4;
#pragma unroll
            for (int r = 0; r < 4; ++r) {
                float v = acc[i][jj][r] + bv;
                s += v; s2 += v * v;
                Yb[(size_t)(jr + r) * 256 + m] = f2b(v);
            }
        }
        s += __shfl_xor(s, 16); s += __shfl_xor(s, 32);
        s2 += __shfl_xor(s2, 16); s2 += __shfl_xor(s2, 32);
        if (q == 0) {
            atomicAdd(&stats[m], s);
            atomicAdd(&stats[256 + m], s2);
        }
    }
}

// ---------- BN1+ReLU apply (inline finalize) bf16 -> bf16 ----------
__global__ __launch_bounds__(256) void apply1_kernel(const u16* __restrict__ Y1,
                                                     const float* __restrict__ stats,
                                                     const float* __restrict__ g,
                                                     const float* __restrict__ be,
                                                     u16* __restrict__ X2) {
    size_t i = ((size_t)blockIdx.x * 256 + threadIdx.x) * 4;
    int m = (int)(i & 255);
    float4 sm = *(const float4*)&stats[m];
    float4 sq = *(const float4*)&stats[256 + m];
    float4 gg = *(const float4*)&g[m];
    float4 bb = *(const float4*)&be[m];
    const float inv = 1.f / 32768.f;
    float mean, var, aa[4], ss[4];
    mean = sm.x * inv; var = sq.x * inv - mean * mean; aa[0] = gg.x * rsqrtf(var + 1e-5f); ss[0] = bb.x - mean * aa[0];
    mean = sm.y * inv; var = sq.y * inv - mean * mean; aa[1] = gg.y * rsqrtf(var + 1e-5f); ss[1] = bb.y - mean * aa[1];
    mean = sm.z * inv; var = sq.z * inv - mean * mean; aa[2] = gg.z * rsqrtf(var + 1e-5f); ss[2] = bb.z - mean * aa[2];
    mean = sm.w * inv; var = sq.w * inv - mean * mean; aa[3] = gg.w * rsqrtf(var + 1e-5f); ss[3] = bb.w - mean * aa[3];
    ushort4 v = *(const ushort4*)&Y1[i];
    ushort4 o;
    o.x = f2b(fmaxf(b2f(v.x) * aa[0] + ss[0], 0.f));
    o.y = f2b(fmaxf(b2f(v.y) * aa[1] + ss[1], 0.f));
    o.z = f2b(fmaxf(b2f(v.z) * aa[2] + ss[2], 0.f));
    o.w = f2b(fmaxf(b2f(v.w) * aa[3] + ss[3], 0.f));
    *(ushort4*)&X2[i] = o;
}

// ---------- BN2+ReLU (inline finalize) + transpose [j][o] -> out[b][o][n] ----------
__global__ __launch_bounds__(256) void final_out_kernel(const u16* __restrict__ Y2,
                                                        const float* __restrict__ stats,
                                                        const float* __restrict__ g,
                                                        const float* __restrict__ be,
                                                        float* __restrict__ out) {
    __shared__ float t[64][65];
    int j0 = blockIdx.x * 64, o0 = blockIdx.y * 64;
    int tid = threadIdx.x;
    int c4 = (tid & 15) * 4, rw = tid >> 4;
#pragma unroll
    for (int p = 0; p < 4; ++p) {
        int jl = p * 16 + rw;
        ushort4 v = *(const ushort4*)&Y2[(size_t)(j0 + jl) * 256 + o0 + c4];
        t[jl][c4] = b2f(v.x); t[jl][c4 + 1] = b2f(v.y);
        t[jl][c4 + 2] = b2f(v.z); t[jl][c4 + 3] = b2f(v.w);
    }
    __syncthreads();
    int b = j0 >> 13, n0 = j0 & 8191;
    const float inv = 1.f / 32768.f;
#pragma unroll
    for (int p = 0; p < 4; ++p) {
        int ol = p * 16 + rw;
        int o = o0 + ol;
        float mean = stats[o] * inv;
        float var = stats[256 + o] * inv - mean * mean;
        float a = g[o] * rsqrtf(var + 1e-5f);
        float s = be[o] - mean * a;
        float4 v;
        v.x = fmaxf(t[c4][ol] * a + s, 0.f);
        v.y = fmaxf(t[c4 + 1][ol] * a + s, 0.f);
        v.z = fmaxf(t[c4 + 2][ol] * a + s, 0.f);
        v.w = fmaxf(t[c4 + 3][ol] * a + s, 0.f);
        *(float4*)&out[(size_t)b * 2097152 + (size_t)o * 8192 + n0 + c4] = v;
    }
}

extern "C" void kernel_launch(void* const* d_in, const int* in_sizes, int n_in,
                              void* d_out, int out_size, void* d_ws, size_t ws_size,
                              hipStream_t stream) {
    const float* pos1 = (const float*)d_in[0];
    const float* pos2 = (const float*)d_in[1];
    const float* feature1 = (const float*)d_in[2];
    const float* feature2 = (const float*)d_in[3];
    const float* W1 = (const float*)d_in[4];
    const float* b1 = (const float*)d_in[5];
    const float* g1 = (const float*)d_in[6];
    const float* be1 = (const float*)d_in[7];
    const float* W2 = (const float*)d_in[8];
    const float* b2 = (const float*)d_in[9];
    const float* g2 = (const float*)d_in[10];
    const float* be2 = (const float*)d_in[11];

    char* ws = (char*)d_ws;
    int*   IDX    = (int*)(ws + 0);                 // 393216 B
    float* WGT    = (float*)(ws + 393216);          // 393216 B
    u16*   W1B    = (u16*)(ws + 786432);            // 196608 B
    u16*   W2B    = (u16*)(ws + 983040);            // 131072 B (contiguous after W1B)
    float* STATS  = (float*)(ws + 1114112);         // 4096 B: sum1/sq1/sum2/sq2
    u16*   F2T    = (u16*)(ws + 1118208);           // 4 MiB  [4][2048][256]
    u16*   F1T    = (u16*)(ws + 5312512);           // 8 MiB  [4][8192][128]
    u16*   INTERP = (u16*)(ws + 13701120);          // 16 MiB [32768][256]
    u16*   Y1     = (u16*)(ws + 30478336);          // 16 MiB [32768][256]
    u16*   X2     = (u16*)(ws + 47255552);          // 16 MiB
    u16*   Y2     = (u16*)(ws + 64032768);          // 16 MiB
    float* OUT    = (float*)d_out;

    hipMemsetAsync(STATS, 0, 1024 * sizeof(float), stream);
    prep_kernel<<<NB_NN + NB_CVT + NB_T2 + NB_T1, 256, 0, stream>>>(
        W1, W2, W1B, feature2, F2T, feature1, F1T, pos1, pos2, IDX, WGT);
    gather_kernel<<<8192, 256, 0, stream>>>(F2T, IDX, WGT, INTERP);
    gemm_kernel<384, true><<<dim3(256, 2), 256, 0, stream>>>(INTERP, F1T, W1B, b1, Y1, STATS);
    apply1_kernel<<<8192, 256, 0, stream>>>(Y1, STATS, g1, be1, X2);
    gemm_kernel<256, false><<<dim3(256, 2), 256, 0, stream>>>(X2, nullptr, W2B, b2, Y2, STATS + 512);
    final_out_kernel<<<dim3(512, 4), 256, 0, stream>>>(Y2, STATS + 512, g2, be2, OUT);
}

// Round 7
// 204.644 us; speedup vs baseline: 1.0792x; 1.0212x over previous
//
#include <hip/hip_runtime.h>
#include <hip/hip_bf16.h>
#include <cstdint>

typedef unsigned short u16;
typedef unsigned int u32;
typedef unsigned long long u64;
typedef __bf16 bf16x8 __attribute__((ext_vector_type(8)));
typedef float f32x4 __attribute__((ext_vector_type(4)));
typedef u16 u16x8 __attribute__((ext_vector_type(8)));

// ---------- helpers ----------
__device__ __forceinline__ u16 f2b(float f) {          // fp32 -> bf16 RNE
    unsigned int u = __float_as_uint(f);
    u += 0x7fffu + ((u >> 16) & 1u);
    return (u16)(u >> 16);
}
__device__ __forceinline__ float b2f(u16 h) {
    return __uint_as_float(((unsigned int)h) << 16);
}
__device__ __forceinline__ void async_cp16(void* lds, const void* g) {
    __builtin_amdgcn_global_load_lds((const __attribute__((address_space(1))) void*)g,
                                     (__attribute__((address_space(3))) void*)lds, 16, 0, 0);
}
// monotone unsigned mapping of float bits (order-preserving, EXACT)
__device__ __forceinline__ u32 fmono(float f) {
    u32 u = __float_as_uint(f);
    return u ^ (((u32)((int)u >> 31)) | 0x80000000u);
}
__device__ __forceinline__ u64 shfl_xor_u64(u64 v, int mask) {
    u32 lo = (u32)v, hi = (u32)(v >> 32);
    lo = (u32)__shfl_xor((int)lo, mask);
    hi = (u32)__shfl_xor((int)hi, mask);
    return ((u64)hi << 32) | lo;
}
// insert exact key into descending top-3 (keys unique: idx field breaks ties)
__device__ __forceinline__ void ins3(u64 k, u64& k0, u64& k1, u64& k2) {
    bool c0 = k > k0, c1 = k > k1, c2 = k > k2;
    k2 = c1 ? k1 : (c2 ? k : k2);
    k1 = c0 ? k0 : (c1 ? k : k1);
    k0 = c0 ? k : k0;
}
// padded pk index: one float4 pad every 64 entries -> the 4 chunk-groups of a
// wave (sb = ck*64) land on distinct bank quads {0-3,4-7,8-11,12-15}
__device__ __forceinline__ int pkix(int i) { return i + (i >> 6); }

// ================= prep kernel: three_nn FIRST, then cvt + transposes =================
// blocks [0,1024): three_nn, 32 queries/block, 2 q/thread, 2 S-halves of 1024
// blocks [1024,1184): W1/W2 -> bf16 (40960 float4)
// blocks [1184,1696): feature2 [4][256][2048] -> F2T [4][2048][256] bf16
// blocks [1696,2720): feature1 [4][128][8192] -> F1T [4][8192][128] bf16
#define NB_NN  1024
#define NB_CVT 160
#define NB_T2  512
#define NB_T1  1024

__global__ __launch_bounds__(256, 8) void prep_kernel(const float* __restrict__ w1,
                                                      const float* __restrict__ w2,
                                                      u16* __restrict__ wb,
                                                      const float* __restrict__ feature2,
                                                      u16* __restrict__ f2t,
                                                      const float* __restrict__ feature1,
                                                      u16* __restrict__ f1t,
                                                      const float* __restrict__ pos1,
                                                      const float* __restrict__ pos2,
                                                      int* __restrict__ idx_out,
                                                      float* __restrict__ w_out) {
    __shared__ __align__(16) char smem[19712];   // 16640 pk-half + 3072 warr -> 8 blocks/CU
    int bi = blockIdx.x;
    int tid = threadIdx.x;

    if (bi >= NB_NN) {
        int ci = bi - NB_NN;
        if (ci < NB_CVT) {
            // ---- weight conversion ----
            int i = ci * 256 + tid;
            if (i < 40960) {
                const float* src = (i < 24576) ? w1 : w2;
                int k = (i < 24576) ? i : (i - 24576);
                float4 v = *(const float4*)&src[(size_t)k * 4];
                ushort4 o;
                o.x = f2b(v.x); o.y = f2b(v.y); o.z = f2b(v.z); o.w = f2b(v.w);
                *(ushort4*)&wb[(size_t)i * 4] = o;
            }
            return;
        }
        // ---- transpose [B][C][S] -> [B][S][C] bf16 ----
        float (*t)[65] = (float (*)[65])smem;    // 16640 B <= 19712
        const float* in; u16* out; int C, S, s0, c0, b;
        if (ci < NB_CVT + NB_T2) {
            int lin = ci - NB_CVT;
            C = 256; S = 2048; in = feature2; out = f2t;
            s0 = (lin & 31) * 64; c0 = ((lin >> 5) & 3) * 64; b = lin >> 7;
        } else {
            int lin = ci - NB_CVT - NB_T2;
            C = 128; S = 8192; in = feature1; out = f1t;
            s0 = (lin & 127) * 64; c0 = ((lin >> 7) & 1) * 64; b = lin >> 8;
        }
        const float* ib = in + (size_t)b * C * S;
        u16* ob = out + (size_t)b * S * C;
        int col = tid & 63, r0 = tid >> 6;
#pragma unroll
        for (int p = 0; p < 16; ++p) {
            int c = p * 4 + r0;
            t[c][col] = ib[(size_t)(c0 + c) * S + s0 + col];
        }
        __syncthreads();
#pragma unroll
        for (int p = 0; p < 16; ++p) {
            int s = p * 4 + r0;
            ob[(size_t)(s0 + s) * C + c0 + col] = f2b(t[col][s]);
        }
        return;
    }

    // ---- three_nn: 32 queries/block (q, q+16 per thread), 2 halves x 16 chunks x 64 ----
    // Exact fp32 t' = dot - 0.5*|p2|^2; strict > keeps lowest index within a chunk;
    // all merges via exact u64 keys (fmono(v)<<32 | 2047-idx): value order + low-idx ties.
    float4* pk = (float4*)smem;                          // padded: 1040 float4 = 16640 B
    u64* warr = (u64*)(smem + 16640);                    // [4 waves][16 pairs][6 keys]
    int j0 = bi * 32;
    int b = j0 >> 13;
    const float* p2 = pos2 + (size_t)b * 3 * 2048;
    int p = tid & 15, ck = tid >> 4;          // ck 0..15
    int wv = tid >> 6, lane = tid & 63;
    int na = (j0 & 8191) + p, nbq = na + 16;
    const float* p1 = pos1 + (size_t)b * 3 * 8192;
    float xa = p1[na], ya = p1[8192 + na], za = p1[16384 + na];
    float xb = p1[nbq], yb = p1[8192 + nbq], zb = p1[16384 + nbq];

    u64 a0k = 0, a1k = 0, a2k = 0, b0k = 0, b1k = 0, b2k = 0;

    for (int half = 0; half < 2; ++half) {
        int hbase = half * 1024;
        // stage this half of candidates
        for (int i = tid; i < 1024; i += 256) {
            int s = hbase + i;
            float x = p2[s], y = p2[2048 + s], z = p2[4096 + s];
            pk[pkix(i)] = make_float4(x, y, z, -0.5f * (x * x + y * y + z * z));
        }
        __syncthreads();

        float ga0 = -3.4e38f, ga1 = -3.4e38f, ga2 = -3.4e38f;
        float gb0 = -3.4e38f, gb1 = -3.4e38f, gb2 = -3.4e38f;
        int ia0 = 0, ia1 = 0, ia2 = 0, ib0 = 0, ib1 = 0, ib2 = 0;
        int sb = ck * 64;
        const float4* pc = pk + pkix(sb);    // 64-chunks never cross a 64-pad boundary
#pragma unroll 4
        for (int it = 0; it < 64; ++it) {
            float4 cd = pc[it];
            int s = sb + it;
            float ta = fmaf(xa, cd.x, fmaf(ya, cd.y, fmaf(za, cd.z, cd.w)));
            float tb = fmaf(xb, cd.x, fmaf(yb, cd.y, fmaf(zb, cd.z, cd.w)));
            bool a0 = ta > ga0, a1 = ta > ga1, a2 = ta > ga2;
            ga2 = a1 ? ga1 : (a2 ? ta : ga2);
            ia2 = a1 ? ia1 : (a2 ? s : ia2);
            ga1 = a0 ? ga0 : (a1 ? ta : ga1);
            ia1 = a0 ? ia0 : (a1 ? s : ia1);
            ga0 = a0 ? ta : ga0;
            ia0 = a0 ? s : ia0;
            bool b0c = tb > gb0, b1c = tb > gb1, b2c = tb > gb2;
            gb2 = b1c ? gb1 : (b2c ? tb : gb2);
            ib2 = b1c ? ib1 : (b2c ? s : ib2);
            gb1 = b0c ? gb0 : (b1c ? tb : gb1);
            ib1 = b0c ? ib0 : (b1c ? s : ib1);
            gb0 = b0c ? tb : gb0;
            ib0 = b0c ? s : ib0;
        }
        __syncthreads();   // all reads done before next half restages

        // fold this half's results into the running exact-key top-3
        int gi0 = hbase + ia0, gi1 = hbase + ia1, gi2 = hbase + ia2;
        int gj0 = hbase + ib0, gj1 = hbase + ib1, gj2 = hbase + ib2;
        ins3(((u64)fmono(ga0) << 32) | (u64)(2047 - gi0), a0k, a1k, a2k);
        ins3(((u64)fmono(ga1) << 32) | (u64)(2047 - gi1), a0k, a1k, a2k);
        ins3(((u64)fmono(ga2) << 32) | (u64)(2047 - gi2), a0k, a1k, a2k);
        ins3(((u64)fmono(gb0) << 32) | (u64)(2047 - gj0), b0k, b1k, b2k);
        ins3(((u64)fmono(gb1) << 32) | (u64)(2047 - gj1), b0k, b1k, b2k);
        ins3(((u64)fmono(gb2) << 32) | (u64)(2047 - gj2), b0k, b1k, b2k);
    }

    // in-wave merge across the 4 chunk-groups (lanes p+16g)
#pragma unroll
    for (int mask = 16; mask <= 32; mask <<= 1) {
        u64 pa0 = shfl_xor_u64(a0k, mask), pa1 = shfl_xor_u64(a1k, mask), pa2 = shfl_xor_u64(a2k, mask);
        u64 pb0 = shfl_xor_u64(b0k, mask), pb1 = shfl_xor_u64(b1k, mask), pb2 = shfl_xor_u64(b2k, mask);
        ins3(pa0, a0k, a1k, a2k); ins3(pa1, a0k, a1k, a2k); ins3(pa2, a0k, a1k, a2k);
        ins3(pb0, b0k, b1k, b2k); ins3(pb1, b0k, b1k, b2k); ins3(pb2, b0k, b1k, b2k);
    }
    if (lane < 16) {
        u64* wr = &warr[(wv * 16 + p) * 6];
        wr[0] = a0k; wr[1] = a1k; wr[2] = a2k;
        wr[3] = b0k; wr[4] = b1k; wr[5] = b2k;
    }
    __syncthreads();
    if (tid < 32) {
        int q = tid;
        int pp = q & 15, off = (q < 16) ? 0 : 3;
        const u64* w0 = &warr[pp * 6];
        u64 k0 = w0[off], k1 = w0[off + 1], k2 = w0[off + 2];
#pragma unroll
        for (int w = 1; w < 4; ++w) {
            const u64* wr = &warr[(w * 16 + pp) * 6];
            ins3(wr[off], k0, k1, k2);
            ins3(wr[off + 1], k0, k1, k2);
            ins3(wr[off + 2], k0, k1, k2);
        }
        int s0 = 2047 - (int)(k0 & 0xFFFFFFFFu);
        int s1 = 2047 - (int)(k1 & 0xFFFFFFFFu);
        int s2 = 2047 - (int)(k2 & 0xFFFFFFFFu);
        int j = j0 + q;
        int n = j & 8191;
        float x1 = p1[n], y1 = p1[8192 + n], z1 = p1[16384 + n];
        float n1 = x1 * x1 + y1 * y1 + z1 * z1;
        // exact weights recomputed from global pos2 (L2-hot; 32 threads only)
        float X0 = p2[s0], Y0 = p2[2048 + s0], Z0 = p2[4096 + s0];
        float X1 = p2[s1], Y1v = p2[2048 + s1], Z1 = p2[4096 + s1];
        float X2 = p2[s2], Y2v = p2[2048 + s2], Z2 = p2[4096 + s2];
        float t0 = x1 * X0 + y1 * Y0 + z1 * Z0 - 0.5f * (X0 * X0 + Y0 * Y0 + Z0 * Z0);
        float t1 = x1 * X1 + y1 * Y1v + z1 * Z1 - 0.5f * (X1 * X1 + Y1v * Y1v + Z1 * Z1);
        float t2 = x1 * X2 + y1 * Y2v + z1 * Z2 - 0.5f * (X2 * X2 + Y2v * Y2v + Z2 * Z2);
        float d0 = fmaxf(fmaf(-2.f, t0, n1), 1e-10f);
        float d1 = fmaxf(fmaf(-2.f, t1, n1), 1e-10f);
        float d2 = fmaxf(fmaf(-2.f, t2, n1), 1e-10f);
        float w0v = 1.f / d0, w1v = 1.f / d1, w2v = 1.f / d2;
        float inv = 1.f / (w0v + w1v + w2v);
        idx_out[j * 3] = s0; idx_out[j * 3 + 1] = s1; idx_out[j * 3 + 2] = s2;
        w_out[j * 3] = w0v * inv; w_out[j * 3 + 1] = w1v * inv; w_out[j * 3 + 2] = w2v * inv;
    }
}

// ---------- gather + interpolate -> INTERP [32768][256] bf16 ----------
__global__ __launch_bounds__(256) void gather_kernel(const u16* __restrict__ f2t,
                                                     const int* __restrict__ idx,
                                                     const float* __restrict__ wgt,
                                                     u16* __restrict__ interp) {
    int wv = threadIdx.x >> 6, lane = threadIdx.x & 63;
    int j = blockIdx.x * 4 + wv;
    int b = j >> 13;
    int i0 = idx[j * 3], i1 = idx[j * 3 + 1], i2 = idx[j * 3 + 2];
    float w0 = wgt[j * 3], w1 = wgt[j * 3 + 1], w2 = wgt[j * 3 + 2];
    const u16* r0 = f2t + ((size_t)(b * 2048 + i0)) * 256;
    const u16* r1 = f2t + ((size_t)(b * 2048 + i1)) * 256;
    const u16* r2 = f2t + ((size_t)(b * 2048 + i2)) * 256;
    int c = lane * 4;
    ushort4 v0 = *(const ushort4*)(r0 + c);
    ushort4 v1 = *(const ushort4*)(r1 + c);
    ushort4 v2 = *(const ushort4*)(r2 + c);
    ushort4 o;
    o.x = f2b(w0 * b2f(v0.x) + w1 * b2f(v1.x) + w2 * b2f(v2.x));
    o.y = f2b(w0 * b2f(v0.y) + w1 * b2f(v1.y) + w2 * b2f(v2.y));
    o.z = f2b(w0 * b2f(v0.z) + w1 * b2f(v1.z) + w2 * b2f(v2.z));
    o.w = f2b(w0 * b2f(v0.w) + w1 * b2f(v1.w) + w2 * b2f(v2.w));
    *(ushort4*)(interp + (size_t)j * 256 + c) = o;
}

// ---------- GEMM: Yb[j][m] = bf16(sum_k A[j][k]*Bw[m][k] + bias[m]), fused BN stats ----------
// SPLIT: A = [A1 (k<256, stride 256) | A2 (k>=256, stride 128)]
// FUSE:  A = relu(bn1(A1)) applied in-register during staging (A1 = Y1 bf16, stride 256)
template <int KT, bool SPLIT, bool FUSE>
__global__ __launch_bounds__(256, 2) void gemm_kernel(const u16* __restrict__ A1,
                                                      const u16* __restrict__ A2,
                                                      const u16* __restrict__ Bw,
                                                      const float* __restrict__ bias,
                                                      const float* __restrict__ stats_in,
                                                      const float* __restrict__ g_in,
                                                      const float* __restrict__ be_in,
                                                      u16* __restrict__ Yb,
                                                      float* __restrict__ stats) {
    __shared__ u16 Al[128 * 64];
    __shared__ u16 Bl[128 * 64];
    int tid = threadIdx.x;
    int lane = tid & 63, wv = tid >> 6;
    int j0 = blockIdx.x * 128, m0 = blockIdx.y * 128;
    int l15 = lane & 15, q = lane >> 4;
    int wj = (wv >> 1) * 64, wm = (wv & 1) * 64;
    f32x4 acc[4][4];
#pragma unroll
    for (int i = 0; i < 4; ++i)
#pragma unroll
        for (int jj = 0; jj < 4; ++jj) acc[i][jj] = (f32x4){0.f, 0.f, 0.f, 0.f};

    int rbase = wv * 32;
    int lrow = lane >> 3, lchunk = lane & 7;
    const u16* Bg = Bw + (size_t)m0 * KT;

    for (int k0 = 0; k0 < KT; k0 += 64) {
        if (FUSE) {
            // ---- A-staging with fused BN1+ReLU (same numerics as standalone apply) ----
            int c = k0 + lchunk * 8;
            const float inv = 1.f / 32768.f;
            float aa[8], ssv[8];
#pragma unroll
            for (int e = 0; e < 8; e += 4) {
                float4 sm = *(const float4*)&stats_in[c + e];
                float4 sq = *(const float4*)&stats_in[256 + c + e];
                float4 gg = *(const float4*)&g_in[c + e];
                float4 bb = *(const float4*)&be_in[c + e];
                float m, v;
                m = sm.x * inv; v = sq.x * inv - m * m; aa[e + 0] = gg.x * rsqrtf(v + 1e-5f); ssv[e + 0] = bb.x - m * aa[e + 0];
                m = sm.y * inv; v = sq.y * inv - m * m; aa[e + 1] = gg.y * rsqrtf(v + 1e-5f); ssv[e + 1] = bb.y - m * aa[e + 1];
                m = sm.z * inv; v = sq.z * inv - m * m; aa[e + 2] = gg.z * rsqrtf(v + 1e-5f); ssv[e + 2] = bb.z - m * aa[e + 2];
                m = sm.w * inv; v = sq.w * inv - m * m; aa[e + 3] = gg.w * rsqrtf(v + 1e-5f); ssv[e + 3] = bb.w - m * aa[e + 3];
            }
#pragma unroll
            for (int qq = 0; qq < 4; ++qq) {
                int row = rbase + qq * 8;
                u16x8 y = *(const u16x8*)&A1[(size_t)(j0 + row + lrow) * 256 + c];
                u16x8 o;
#pragma unroll
                for (int e = 0; e < 8; ++e)
                    o[e] = f2b(fmaxf(b2f(y[e]) * aa[e] + ssv[e], 0.f));
                *(u16x8*)&Al[(row + lrow) * 64 + lchunk * 8] = o;
                async_cp16(&Bl[row * 64], Bg + (size_t)(row + lrow) * KT + k0 + lchunk * 8);
            }
        } else {
            const u16* src; int stride;
            if (!SPLIT || k0 < 256) { src = A1 + (size_t)j0 * 256 + k0; stride = 256; }
            else                    { src = A2 + (size_t)j0 * 128 + (k0 - 256); stride = 128; }
#pragma unroll
            for (int qq = 0; qq < 4; ++qq) {
                int row = rbase + qq * 8;   // wave-uniform LDS base; HW adds lane*16B
                async_cp16(&Al[row * 64], src + (size_t)(row + lrow) * stride + lchunk * 8);
                async_cp16(&Bl[row * 64], Bg + (size_t)(row + lrow) * KT + k0 + lchunk * 8);
            }
        }
        __syncthreads();
#pragma unroll
        for (int ks = 0; ks < 2; ++ks) {
            bf16x8 af[4], bfr[4];
#pragma unroll
            for (int i = 0; i < 4; ++i)
                af[i] = *(const bf16x8*)&Al[(wj + i * 16 + l15) * 64 + ks * 32 + q * 8];
#pragma unroll
            for (int i = 0; i < 4; ++i)
                bfr[i] = *(const bf16x8*)&Bl[(wm + i * 16 + l15) * 64 + ks * 32 + q * 8];
#pragma unroll
            for (int i = 0; i < 4; ++i)
#pragma unroll
                for (int jj = 0; jj < 4; ++jj)
                    acc[i][jj] = __builtin_amdgcn_mfma_f32_16x16x32_bf16(af[i], bfr[jj],
                                                                         acc[i][jj], 0, 0, 0);
        }
        __syncthreads();
    }
    // epilogue: D col = lane&15 (channel m), row = q*4+reg (j); fused per-channel sum/sumsq
#pragma unroll
    for (int jj = 0; jj < 4; ++jj) {
        int m = m0 + wm + jj * 16 + l15;
        float bv = bias[m];
        float s = 0.f, s2 = 0.f;
#pragma unroll
        for (int i = 0; i < 4; ++i) {
            int jr = j0 + wj + i * 16 + q * 4;
#pragma unroll
            for (int r = 0; r < 4; ++r) {
                float v = acc[i][jj][r] + bv;
                s += v; s2 += v * v;
                Yb[(size_t)(jr + r) * 256 + m] = f2b(v);
            }
        }
        s += __shfl_xor(s, 16); s += __shfl_xor(s, 32);
        s2 += __shfl_xor(s2, 16); s2 += __shfl_xor(s2, 32);
        if (q == 0) {
            atomicAdd(&stats[m], s);
            atomicAdd(&stats[256 + m], s2);
        }
    }
}

// ---------- BN2+ReLU (inline finalize) + transpose [j][o] -> out[b][o][n] ----------
__global__ __launch_bounds__(256) void final_out_kernel(const u16* __restrict__ Y2,
                                                        const float* __restrict__ stats,
                                                        const float* __restrict__ g,
                                                        const float* __restrict__ be,
                                                        float* __restrict__ out) {
    __shared__ float t[64][65];
    int j0 = blockIdx.x * 64, o0 = blockIdx.y * 64;
    int tid = threadIdx.x;
    int c4 = (tid & 15) * 4, rw = tid >> 4;
#pragma unroll
    for (int p = 0; p < 4; ++p) {
        int jl = p * 16 + rw;
        ushort4 v = *(const ushort4*)&Y2[(size_t)(j0 + jl) * 256 + o0 + c4];
        t[jl][c4] = b2f(v.x); t[jl][c4 + 1] = b2f(v.y);
        t[jl][c4 + 2] = b2f(v.z); t[jl][c4 + 3] = b2f(v.w);
    }
    __syncthreads();
    int b = j0 >> 13, n0 = j0 & 8191;
    const float inv = 1.f / 32768.f;
#pragma unroll
    for (int p = 0; p < 4; ++p) {
        int ol = p * 16 + rw;
        int o = o0 + ol;
        float mean = stats[o] * inv;
        float var = stats[256 + o] * inv - mean * mean;
        float a = g[o] * rsqrtf(var + 1e-5f);
        float s = be[o] - mean * a;
        float4 v;
        v.x = fmaxf(t[c4][ol] * a + s, 0.f);
        v.y = fmaxf(t[c4 + 1][ol] * a + s, 0.f);
        v.z = fmaxf(t[c4 + 2][ol] * a + s, 0.f);
        v.w = fmaxf(t[c4 + 3][ol] * a + s, 0.f);
        *(float4*)&out[(size_t)b * 2097152 + (size_t)o * 8192 + n0 + c4] = v;
    }
}

extern "C" void kernel_launch(void* const* d_in, const int* in_sizes, int n_in,
                              void* d_out, int out_size, void* d_ws, size_t ws_size,
                              hipStream_t stream) {
    const float* pos1 = (const float*)d_in[0];
    const float* pos2 = (const float*)d_in[1];
    const float* feature1 = (const float*)d_in[2];
    const float* feature2 = (const float*)d_in[3];
    const float* W1 = (const float*)d_in[4];
    const float* b1 = (const float*)d_in[5];
    const float* g1 = (const float*)d_in[6];
    const float* be1 = (const float*)d_in[7];
    const float* W2 = (const float*)d_in[8];
    const float* b2 = (const float*)d_in[9];
    const float* g2 = (const float*)d_in[10];
    const float* be2 = (const float*)d_in[11];

    char* ws = (char*)d_ws;
    int*   IDX    = (int*)(ws + 0);                 // 393216 B
    float* WGT    = (float*)(ws + 393216);          // 393216 B
    u16*   W1B    = (u16*)(ws + 786432);            // 196608 B
    u16*   W2B    = (u16*)(ws + 983040);            // 131072 B (contiguous after W1B)
    float* STATS  = (float*)(ws + 1114112);         // 4096 B: sum1/sq1/sum2/sq2
    u16*   F2T    = (u16*)(ws + 1118208);           // 4 MiB  [4][2048][256]
    u16*   F1T    = (u16*)(ws + 5312512);           // 8 MiB  [4][8192][128]
    u16*   INTERP = (u16*)(ws + 13701120);          // 16 MiB [32768][256]
    u16*   Y1     = (u16*)(ws + 30478336);          // 16 MiB [32768][256]
    u16*   Y2     = (u16*)(ws + 47255552);          // 16 MiB
    float* OUT    = (float*)d_out;

    hipMemsetAsync(STATS, 0, 1024 * sizeof(float), stream);
    prep_kernel<<<NB_NN + NB_CVT + NB_T2 + NB_T1, 256, 0, stream>>>(
        W1, W2, W1B, feature2, F2T, feature1, F1T, pos1, pos2, IDX, WGT);
    gather_kernel<<<8192, 256, 0, stream>>>(F2T, IDX, WGT, INTERP);
    gemm_kernel<384, true, false><<<dim3(256, 2), 256, 0, stream>>>(
        INTERP, F1T, W1B, b1, nullptr, nullptr, nullptr, Y1, STATS);
    gemm_kernel<256, false, true><<<dim3(256, 2), 256, 0, stream>>>(
        Y1, nullptr, W2B, b2, STATS, g1, be1, Y2, STATS + 512);
    final_out_kernel<<<dim3(512, 4), 256, 0, stream>>>(Y2, STATS + 512, g2, be2, OUT);
}

// Round 8
// 201.864 us; speedup vs baseline: 1.0941x; 1.0138x over previous
//
#include <hip/hip_runtime.h>
#include <hip/hip_bf16.h>
#include <cstdint>

typedef unsigned short u16;
typedef unsigned int u32;
typedef unsigned long long u64;
typedef __bf16 bf16x8 __attribute__((ext_vector_type(8)));
typedef float f32x4 __attribute__((ext_vector_type(4)));
typedef u16 u16x8 __attribute__((ext_vector_type(8)));

// ---------- helpers ----------
__device__ __forceinline__ u16 f2b(float f) {          // fp32 -> bf16 RNE
    unsigned int u = __float_as_uint(f);
    u += 0x7fffu + ((u >> 16) & 1u);
    return (u16)(u >> 16);
}
__device__ __forceinline__ float b2f(u16 h) {
    return __uint_as_float(((unsigned int)h) << 16);
}
__device__ __forceinline__ void async_cp16(void* lds, const void* g) {
    __builtin_amdgcn_global_load_lds((const __attribute__((address_space(1))) void*)g,
                                     (__attribute__((address_space(3))) void*)lds, 16, 0, 0);
}
// monotone unsigned mapping of float bits (order-preserving, EXACT)
__device__ __forceinline__ u32 fmono(float f) {
    u32 u = __float_as_uint(f);
    return u ^ (((u32)((int)u >> 31)) | 0x80000000u);
}
__device__ __forceinline__ u64 shfl_xor_u64(u64 v, int mask) {
    u32 lo = (u32)v, hi = (u32)(v >> 32);
    lo = (u32)__shfl_xor((int)lo, mask);
    hi = (u32)__shfl_xor((int)hi, mask);
    return ((u64)hi << 32) | lo;
}
// insert exact key into descending top-3 (keys unique: idx field breaks ties)
__device__ __forceinline__ void ins3(u64 k, u64& k0, u64& k1, u64& k2) {
    bool c0 = k > k0, c1 = k > k1, c2 = k > k2;
    k2 = c1 ? k1 : (c2 ? k : k2);
    k1 = c0 ? k0 : (c1 ? k : k1);
    k0 = c0 ? k : k0;
}
// padded pk index: one float4 pad every 64 entries
__device__ __forceinline__ int pkix(int i) { return i + (i >> 6); }

// ================= prep kernel: three_nn FIRST, then cvt + transposes =================
#define NB_NN  1024
#define NB_CVT 160
#define NB_T2  512
#define NB_T1  1024

__global__ __launch_bounds__(256, 8) void prep_kernel(const float* __restrict__ w1,
                                                      const float* __restrict__ w2,
                                                      u16* __restrict__ wb,
                                                      const float* __restrict__ feature2,
                                                      u16* __restrict__ f2t,
                                                      const float* __restrict__ feature1,
                                                      u16* __restrict__ f1t,
                                                      const float* __restrict__ pos1,
                                                      const float* __restrict__ pos2,
                                                      int* __restrict__ idx_out,
                                                      float* __restrict__ w_out) {
    __shared__ __align__(16) char smem[19712];   // 16640 pk-half + 3072 warr -> 8 blocks/CU
    int bi = blockIdx.x;
    int tid = threadIdx.x;

    if (bi >= NB_NN) {
        int ci = bi - NB_NN;
        if (ci < NB_CVT) {
            int i = ci * 256 + tid;
            if (i < 40960) {
                const float* src = (i < 24576) ? w1 : w2;
                int k = (i < 24576) ? i : (i - 24576);
                float4 v = *(const float4*)&src[(size_t)k * 4];
                ushort4 o;
                o.x = f2b(v.x); o.y = f2b(v.y); o.z = f2b(v.z); o.w = f2b(v.w);
                *(ushort4*)&wb[(size_t)i * 4] = o;
            }
            return;
        }
        // ---- transpose [B][C][S] -> [B][S][C] bf16 ----
        float (*t)[65] = (float (*)[65])smem;
        const float* in; u16* out; int C, S, s0, c0, b;
        if (ci < NB_CVT + NB_T2) {
            int lin = ci - NB_CVT;
            C = 256; S = 2048; in = feature2; out = f2t;
            s0 = (lin & 31) * 64; c0 = ((lin >> 5) & 3) * 64; b = lin >> 7;
        } else {
            int lin = ci - NB_CVT - NB_T2;
            C = 128; S = 8192; in = feature1; out = f1t;
            s0 = (lin & 127) * 64; c0 = ((lin >> 7) & 1) * 64; b = lin >> 8;
        }
        const float* ib = in + (size_t)b * C * S;
        u16* ob = out + (size_t)b * S * C;
        int col = tid & 63, r0 = tid >> 6;
#pragma unroll
        for (int p = 0; p < 16; ++p) {
            int c = p * 4 + r0;
            t[c][col] = ib[(size_t)(c0 + c) * S + s0 + col];
        }
        __syncthreads();
#pragma unroll
        for (int p = 0; p < 16; ++p) {
            int s = p * 4 + r0;
            ob[(size_t)(s0 + s) * C + c0 + col] = f2b(t[col][s]);
        }
        return;
    }

    // ---- three_nn: 32 queries/block (q, q+16 per thread), 2 halves x 16 chunks x 64 ----
    float4* pk = (float4*)smem;                          // padded: 1040 float4 = 16640 B
    u64* warr = (u64*)(smem + 16640);
    int j0 = bi * 32;
    int b = j0 >> 13;
    const float* p2 = pos2 + (size_t)b * 3 * 2048;
    int p = tid & 15, ck = tid >> 4;
    int wv = tid >> 6, lane = tid & 63;
    int na = (j0 & 8191) + p, nbq = na + 16;
    const float* p1 = pos1 + (size_t)b * 3 * 8192;
    float xa = p1[na], ya = p1[8192 + na], za = p1[16384 + na];
    float xb = p1[nbq], yb = p1[8192 + nbq], zb = p1[16384 + nbq];

    u64 a0k = 0, a1k = 0, a2k = 0, b0k = 0, b1k = 0, b2k = 0;

    for (int half = 0; half < 2; ++half) {
        int hbase = half * 1024;
        for (int i = tid; i < 1024; i += 256) {
            int s = hbase + i;
            float x = p2[s], y = p2[2048 + s], z = p2[4096 + s];
            pk[pkix(i)] = make_float4(x, y, z, -0.5f * (x * x + y * y + z * z));
        }
        __syncthreads();

        float ga0 = -3.4e38f, ga1 = -3.4e38f, ga2 = -3.4e38f;
        float gb0 = -3.4e38f, gb1 = -3.4e38f, gb2 = -3.4e38f;
        int ia0 = 0, ia1 = 0, ia2 = 0, ib0 = 0, ib1 = 0, ib2 = 0;
        int sb = ck * 64;
        const float4* pc = pk + pkix(sb);
#pragma unroll 4
        for (int it = 0; it < 64; ++it) {
            float4 cd = pc[it];
            int s = sb + it;
            float ta = fmaf(xa, cd.x, fmaf(ya, cd.y, fmaf(za, cd.z, cd.w)));
            float tb = fmaf(xb, cd.x, fmaf(yb, cd.y, fmaf(zb, cd.z, cd.w)));
            bool a0 = ta > ga0, a1 = ta > ga1, a2 = ta > ga2;
            ga2 = a1 ? ga1 : (a2 ? ta : ga2);
            ia2 = a1 ? ia1 : (a2 ? s : ia2);
            ga1 = a0 ? ga0 : (a1 ? ta : ga1);
            ia1 = a0 ? ia0 : (a1 ? s : ia1);
            ga0 = a0 ? ta : ga0;
            ia0 = a0 ? s : ia0;
            bool b0c = tb > gb0, b1c = tb > gb1, b2c = tb > gb2;
            gb2 = b1c ? gb1 : (b2c ? tb : gb2);
            ib2 = b1c ? ib1 : (b2c ? s : ib2);
            gb1 = b0c ? gb0 : (b1c ? tb : gb1);
            ib1 = b0c ? ib0 : (b1c ? s : ib1);
            gb0 = b0c ? tb : gb0;
            ib0 = b0c ? s : ib0;
        }
        __syncthreads();

        int gi0 = hbase + ia0, gi1 = hbase + ia1, gi2 = hbase + ia2;
        int gj0 = hbase + ib0, gj1 = hbase + ib1, gj2 = hbase + ib2;
        ins3(((u64)fmono(ga0) << 32) | (u64)(2047 - gi0), a0k, a1k, a2k);
        ins3(((u64)fmono(ga1) << 32) | (u64)(2047 - gi1), a0k, a1k, a2k);
        ins3(((u64)fmono(ga2) << 32) | (u64)(2047 - gi2), a0k, a1k, a2k);
        ins3(((u64)fmono(gb0) << 32) | (u64)(2047 - gj0), b0k, b1k, b2k);
        ins3(((u64)fmono(gb1) << 32) | (u64)(2047 - gj1), b0k, b1k, b2k);
        ins3(((u64)fmono(gb2) << 32) | (u64)(2047 - gj2), b0k, b1k, b2k);
    }

#pragma unroll
    for (int mask = 16; mask <= 32; mask <<= 1) {
        u64 pa0 = shfl_xor_u64(a0k, mask), pa1 = shfl_xor_u64(a1k, mask), pa2 = shfl_xor_u64(a2k, mask);
        u64 pb0 = shfl_xor_u64(b0k, mask), pb1 = shfl_xor_u64(b1k, mask), pb2 = shfl_xor_u64(b2k, mask);
        ins3(pa0, a0k, a1k, a2k); ins3(pa1, a0k, a1k, a2k); ins3(pa2, a0k, a1k, a2k);
        ins3(pb0, b0k, b1k, b2k); ins3(pb1, b0k, b1k, b2k); ins3(pb2, b0k, b1k, b2k);
    }
    if (lane < 16) {
        u64* wr = &warr[(wv * 16 + p) * 6];
        wr[0] = a0k; wr[1] = a1k; wr[2] = a2k;
        wr[3] = b0k; wr[4] = b1k; wr[5] = b2k;
    }
    __syncthreads();
    if (tid < 32) {
        int q = tid;
        int pp = q & 15, off = (q < 16) ? 0 : 3;
        const u64* w0 = &warr[pp * 6];
        u64 k0 = w0[off], k1 = w0[off + 1], k2 = w0[off + 2];
#pragma unroll
        for (int w = 1; w < 4; ++w) {
            const u64* wr = &warr[(w * 16 + pp) * 6];
            ins3(wr[off], k0, k1, k2);
            ins3(wr[off + 1], k0, k1, k2);
            ins3(wr[off + 2], k0, k1, k2);
        }
        int s0 = 2047 - (int)(k0 & 0xFFFFFFFFu);
        int s1 = 2047 - (int)(k1 & 0xFFFFFFFFu);
        int s2 = 2047 - (int)(k2 & 0xFFFFFFFFu);
        int j = j0 + q;
        int n = j & 8191;
        float x1 = p1[n], y1 = p1[8192 + n], z1 = p1[16384 + n];
        float n1 = x1 * x1 + y1 * y1 + z1 * z1;
        float X0 = p2[s0], Y0 = p2[2048 + s0], Z0 = p2[4096 + s0];
        float X1 = p2[s1], Y1v = p2[2048 + s1], Z1 = p2[4096 + s1];
        float X2 = p2[s2], Y2v = p2[2048 + s2], Z2 = p2[4096 + s2];
        float t0 = x1 * X0 + y1 * Y0 + z1 * Z0 - 0.5f * (X0 * X0 + Y0 * Y0 + Z0 * Z0);
        float t1 = x1 * X1 + y1 * Y1v + z1 * Z1 - 0.5f * (X1 * X1 + Y1v * Y1v + Z1 * Z1);
        float t2 = x1 * X2 + y1 * Y2v + z1 * Z2 - 0.5f * (X2 * X2 + Y2v * Y2v + Z2 * Z2);
        float d0 = fmaxf(fmaf(-2.f, t0, n1), 1e-10f);
        float d1 = fmaxf(fmaf(-2.f, t1, n1), 1e-10f);
        float d2 = fmaxf(fmaf(-2.f, t2, n1), 1e-10f);
        float w0v = 1.f / d0, w1v = 1.f / d1, w2v = 1.f / d2;
        float inv = 1.f / (w0v + w1v + w2v);
        idx_out[j * 3] = s0; idx_out[j * 3 + 1] = s1; idx_out[j * 3 + 2] = s2;
        w_out[j * 3] = w0v * inv; w_out[j * 3 + 1] = w1v * inv; w_out[j * 3 + 2] = w2v * inv;
    }
}

// ---------- gather + interpolate -> INTERP [32768][256] bf16 ----------
__global__ __launch_bounds__(256) void gather_kernel(const u16* __restrict__ f2t,
                                                     const int* __restrict__ idx,
                                                     const float* __restrict__ wgt,
                                                     u16* __restrict__ interp) {
    int wv = threadIdx.x >> 6, lane = threadIdx.x & 63;
    int j = blockIdx.x * 4 + wv;
    int b = j >> 13;
    int i0 = idx[j * 3], i1 = idx[j * 3 + 1], i2 = idx[j * 3 + 2];
    float w0 = wgt[j * 3], w1 = wgt[j * 3 + 1], w2 = wgt[j * 3 + 2];
    const u16* r0 = f2t + ((size_t)(b * 2048 + i0)) * 256;
    const u16* r1 = f2t + ((size_t)(b * 2048 + i1)) * 256;
    const u16* r2 = f2t + ((size_t)(b * 2048 + i2)) * 256;
    int c = lane * 4;
    ushort4 v0 = *(const ushort4*)(r0 + c);
    ushort4 v1 = *(const ushort4*)(r1 + c);
    ushort4 v2 = *(const ushort4*)(r2 + c);
    ushort4 o;
    o.x = f2b(w0 * b2f(v0.x) + w1 * b2f(v1.x) + w2 * b2f(v2.x));
    o.y = f2b(w0 * b2f(v0.y) + w1 * b2f(v1.y) + w2 * b2f(v2.y));
    o.z = f2b(w0 * b2f(v0.z) + w1 * b2f(v1.z) + w2 * b2f(v2.z));
    o.w = f2b(w0 * b2f(v0.w) + w1 * b2f(v1.w) + w2 * b2f(v2.w));
    *(ushort4*)(interp + (size_t)j * 256 + c) = o;
}

// ---------- GEMM: Yb[j][m] = bf16(sum_k A[j][k]*Bw[m][k] + bias[m]), fused BN stats ----------
// SPLIT: A = [A1 (k<256, stride 256) | A2 (k>=256, stride 128)]
// FUSE:  A = relu(bn1(A1)) applied in-register during staging (BN factors from LDS table)
// Epilogue: LDS bounce (stride 136) -> fully coalesced u16x8 stores of the Y tile.
template <int KT, bool SPLIT, bool FUSE>
__global__ __launch_bounds__(256, 2) void gemm_kernel(const u16* __restrict__ A1,
                                                      const u16* __restrict__ A2,
                                                      const u16* __restrict__ Bw,
                                                      const float* __restrict__ bias,
                                                      const float* __restrict__ stats_in,
                                                      const float* __restrict__ g_in,
                                                      const float* __restrict__ be_in,
                                                      u16* __restrict__ Yb,
                                                      float* __restrict__ stats) {
    __shared__ __align__(16) char smemA[36864];
    u16* Al = (u16*)smemA;                       // [128][64], k-loop
    u16* Bl = (u16*)(smemA + 16384);             // [128][64], k-loop
    u16* T  = (u16*)smemA;                       // [128][136] epilogue bounce (overlays Al/Bl)
    float2* BNT = (float2*)(smemA + 34816);      // 256 x (scale, shift), persistent (FUSE)
    int tid = threadIdx.x;
    int lane = tid & 63, wv = tid >> 6;
    int j0 = blockIdx.x * 128, m0 = blockIdx.y * 128;
    int l15 = lane & 15, q = lane >> 4;
    int wj = (wv >> 1) * 64, wm = (wv & 1) * 64;
    f32x4 acc[4][4];
#pragma unroll
    for (int i = 0; i < 4; ++i)
#pragma unroll
        for (int jj = 0; jj < 4; ++jj) acc[i][jj] = (f32x4){0.f, 0.f, 0.f, 0.f};

    if (FUSE) {
        // one-time BN1 factor table (identical per-channel math to the reference fold)
        int m = tid;
        const float inv = 1.f / 32768.f;
        float mean = stats_in[m] * inv;
        float var = stats_in[256 + m] * inv - mean * mean;
        float a = g_in[m] * rsqrtf(var + 1e-5f);
        BNT[m] = make_float2(a, be_in[m] - mean * a);
        __syncthreads();
    }

    int rbase = wv * 32;
    int lrow = lane >> 3, lchunk = lane & 7;
    const u16* Bg = Bw + (size_t)m0 * KT;

    for (int k0 = 0; k0 < KT; k0 += 64) {
        if (FUSE) {
            int c = k0 + lchunk * 8;
            float2 bn[8];
#pragma unroll
            for (int e = 0; e < 8; ++e) bn[e] = BNT[c + e];
#pragma unroll
            for (int qq = 0; qq < 4; ++qq) {
                int row = rbase + qq * 8;
                u16x8 y = *(const u16x8*)&A1[(size_t)(j0 + row + lrow) * 256 + c];
                u16x8 o;
#pragma unroll
                for (int e = 0; e < 8; ++e)
                    o[e] = f2b(fmaxf(b2f(y[e]) * bn[e].x + bn[e].y, 0.f));
                *(u16x8*)&Al[(row + lrow) * 64 + lchunk * 8] = o;
                async_cp16(&Bl[row * 64], Bg + (size_t)(row + lrow) * KT + k0 + lchunk * 8);
            }
        } else {
            const u16* src; int stride;
            if (!SPLIT || k0 < 256) { src = A1 + (size_t)j0 * 256 + k0; stride = 256; }
            else                    { src = A2 + (size_t)j0 * 128 + (k0 - 256); stride = 128; }
#pragma unroll
            for (int qq = 0; qq < 4; ++qq) {
                int row = rbase + qq * 8;   // wave-uniform LDS base; HW adds lane*16B
                async_cp16(&Al[row * 64], src + (size_t)(row + lrow) * stride + lchunk * 8);
                async_cp16(&Bl[row * 64], Bg + (size_t)(row + lrow) * KT + k0 + lchunk * 8);
            }
        }
        __syncthreads();
#pragma unroll
        for (int ks = 0; ks < 2; ++ks) {
            bf16x8 af[4], bfr[4];
#pragma unroll
            for (int i = 0; i < 4; ++i)
                af[i] = *(const bf16x8*)&Al[(wj + i * 16 + l15) * 64 + ks * 32 + q * 8];
#pragma unroll
            for (int i = 0; i < 4; ++i)
                bfr[i] = *(const bf16x8*)&Bl[(wm + i * 16 + l15) * 64 + ks * 32 + q * 8];
#pragma unroll
            for (int i = 0; i < 4; ++i)
#pragma unroll
                for (int jj = 0; jj < 4; ++jj)
                    acc[i][jj] = __builtin_amdgcn_mfma_f32_16x16x32_bf16(af[i], bfr[jj],
                                                                         acc[i][jj], 0, 0, 0);
        }
        __syncthreads();
    }
    // epilogue: stats + bf16 tile into LDS (D col = lane&15 -> m, row = q*4+reg -> j)
#pragma unroll
    for (int jj = 0; jj < 4; ++jj) {
        int ml = wm + jj * 16 + l15;
        float bv = bias[m0 + ml];
        float s = 0.f, s2 = 0.f;
#pragma unroll
        for (int i = 0; i < 4; ++i) {
            int jl = wj + i * 16 + q * 4;
#pragma unroll
            for (int r = 0; r < 4; ++r) {
                float v = acc[i][jj][r] + bv;
                s += v; s2 += v * v;
                T[(jl + r) * 136 + ml] = f2b(v);
            }
        }
        s += __shfl_xor(s, 16); s += __shfl_xor(s, 32);
        s2 += __shfl_xor(s2, 16); s2 += __shfl_xor(s2, 32);
        if (q == 0) {
            atomicAdd(&stats[m0 + ml], s);
            atomicAdd(&stats[256 + m0 + ml], s2);
        }
    }
    __syncthreads();
    // coalesced store: each wave covers 4 rows x 128 ch per iter (256 B segments)
#pragma unroll
    for (int it = 0; it < 8; ++it) {
        int jl = it * 16 + wv * 4 + q;
        u16x8 v = *(const u16x8*)&T[jl * 136 + l15 * 8];
        *(u16x8*)&Yb[(size_t)(j0 + jl) * 256 + m0 + l15 * 8] = v;
    }
}

// ---------- BN2+ReLU (inline finalize) + transpose [j][o] -> out[b][o][n] ----------
__global__ __launch_bounds__(256) void final_out_kernel(const u16* __restrict__ Y2,
                                                        const float* __restrict__ stats,
                                                        const float* __restrict__ g,
                                                        const float* __restrict__ be,
                                                        float* __restrict__ out) {
    __shared__ float t[64][65];
    int j0 = blockIdx.x * 64, o0 = blockIdx.y * 64;
    int tid = threadIdx.x;
    int c4 = (tid & 15) * 4, rw = tid >> 4;
#pragma unroll
    for (int p = 0; p < 4; ++p) {
        int jl = p * 16 + rw;
        ushort4 v = *(const ushort4*)&Y2[(size_t)(j0 + jl) * 256 + o0 + c4];
        t[jl][c4] = b2f(v.x); t[jl][c4 + 1] = b2f(v.y);
        t[jl][c4 + 2] = b2f(v.z); t[jl][c4 + 3] = b2f(v.w);
    }
    __syncthreads();
    int b = j0 >> 13, n0 = j0 & 8191;
    const float inv = 1.f / 32768.f;
#pragma unroll
    for (int p = 0; p < 4; ++p) {
        int ol = p * 16 + rw;
        int o = o0 + ol;
        float mean = stats[o] * inv;
        float var = stats[256 + o] * inv - mean * mean;
        float a = g[o] * rsqrtf(var + 1e-5f);
        float s = be[o] - mean * a;
        float4 v;
        v.x = fmaxf(t[c4][ol] * a + s, 0.f);
        v.y = fmaxf(t[c4 + 1][ol] * a + s, 0.f);
        v.z = fmaxf(t[c4 + 2][ol] * a + s, 0.f);
        v.w = fmaxf(t[c4 + 3][ol] * a + s, 0.f);
        *(float4*)&out[(size_t)b * 2097152 + (size_t)o * 8192 + n0 + c4] = v;
    }
}

extern "C" void kernel_launch(void* const* d_in, const int* in_sizes, int n_in,
                              void* d_out, int out_size, void* d_ws, size_t ws_size,
                              hipStream_t stream) {
    const float* pos1 = (const float*)d_in[0];
    const float* pos2 = (const float*)d_in[1];
    const float* feature1 = (const float*)d_in[2];
    const float* feature2 = (const float*)d_in[3];
    const float* W1 = (const float*)d_in[4];
    const float* b1 = (const float*)d_in[5];
    const float* g1 = (const float*)d_in[6];
    const float* be1 = (const float*)d_in[7];
    const float* W2 = (const float*)d_in[8];
    const float* b2 = (const float*)d_in[9];
    const float* g2 = (const float*)d_in[10];
    const float* be2 = (const float*)d_in[11];

    char* ws = (char*)d_ws;
    int*   IDX    = (int*)(ws + 0);                 // 393216 B
    float* WGT    = (float*)(ws + 393216);          // 393216 B
    u16*   W1B    = (u16*)(ws + 786432);            // 196608 B
    u16*   W2B    = (u16*)(ws + 983040);            // 131072 B (contiguous after W1B)
    float* STATS  = (float*)(ws + 1114112);         // 4096 B: sum1/sq1/sum2/sq2
    u16*   F2T    = (u16*)(ws + 1118208);           // 4 MiB  [4][2048][256]
    u16*   F1T    = (u16*)(ws + 5312512);           // 8 MiB  [4][8192][128]
    u16*   INTERP = (u16*)(ws + 13701120);          // 16 MiB [32768][256]
    u16*   Y1     = (u16*)(ws + 30478336);          // 16 MiB [32768][256]
    u16*   Y2     = (u16*)(ws + 47255552);          // 16 MiB
    float* OUT    = (float*)d_out;

    hipMemsetAsync(STATS, 0, 1024 * sizeof(float), stream);
    prep_kernel<<<NB_NN + NB_CVT + NB_T2 + NB_T1, 256, 0, stream>>>(
        W1, W2, W1B, feature2, F2T, feature1, F1T, pos1, pos2, IDX, WGT);
    gather_kernel<<<8192, 256, 0, stream>>>(F2T, IDX, WGT, INTERP);
    gemm_kernel<384, true, false><<<dim3(256, 2), 256, 0, stream>>>(
        INTERP, F1T, W1B, b1, nullptr, nullptr, nullptr, Y1, STATS);
    gemm_kernel<256, false, true><<<dim3(256, 2), 256, 0, stream>>>(
        Y1, nullptr, W2B, b2, STATS, g1, be1, Y2, STATS + 512);
    final_out_kernel<<<dim3(512, 4), 256, 0, stream>>>(Y2, STATS + 512, g2, be2, OUT);
}

// Round 9
// 199.262 us; speedup vs baseline: 1.1084x; 1.0131x over previous
//
#include <hip/hip_runtime.h>
#include <hip/hip_bf16.h>
#include <cstdint>

typedef unsigned short u16;
typedef unsigned int u32;
typedef unsigned long long u64;
typedef __bf16 bf16x8 __attribute__((ext_vector_type(8)));
typedef float f32x4 __attribute__((ext_vector_type(4)));
typedef u16 u16x8 __attribute__((ext_vector_type(8)));

// ---------- helpers ----------
__device__ __forceinline__ u16 f2b(float f) {          // fp32 -> bf16 RNE
    unsigned int u = __float_as_uint(f);
    u += 0x7fffu + ((u >> 16) & 1u);
    return (u16)(u >> 16);
}
__device__ __forceinline__ float b2f(u16 h) {
    return __uint_as_float(((unsigned int)h) << 16);
}
__device__ __forceinline__ void async_cp16(void* lds, const void* g) {
    __builtin_amdgcn_global_load_lds((const __attribute__((address_space(1))) void*)g,
                                     (__attribute__((address_space(3))) void*)lds, 16, 0, 0);
}
// monotone unsigned mapping of float bits (order-preserving, EXACT)
__device__ __forceinline__ u32 fmono(float f) {
    u32 u = __float_as_uint(f);
    return u ^ (((u32)((int)u >> 31)) | 0x80000000u);
}
__device__ __forceinline__ u64 shfl_xor_u64(u64 v, int mask) {
    u32 lo = (u32)v, hi = (u32)(v >> 32);
    lo = (u32)__shfl_xor((int)lo, mask);
    hi = (u32)__shfl_xor((int)hi, mask);
    return ((u64)hi << 32) | lo;
}
// insert exact key into descending top-3 (keys unique: idx field breaks ties)
__device__ __forceinline__ void ins3(u64 k, u64& k0, u64& k1, u64& k2) {
    bool c0 = k > k0, c1 = k > k1, c2 = k > k2;
    k2 = c1 ? k1 : (c2 ? k : k2);
    k1 = c0 ? k0 : (c1 ? k : k1);
    k0 = c0 ? k : k0;
}
// padded pk index: one float4 pad every 64 entries (chunk groups on distinct banks)
__device__ __forceinline__ int pkix(int i) { return i + (i >> 6); }

// ================= prep kernel: three_nn FIRST, then cvt + transposes =================
// blocks [0,512): three_nn, 64 queries/block, 4 q/thread, 2 S-halves x 16 chunks x 64
#define NB_NN  512
#define NB_CVT 160
#define NB_T2  512
#define NB_T1  1024

__global__ __launch_bounds__(256, 4) void prep_kernel(const float* __restrict__ w1,
                                                      const float* __restrict__ w2,
                                                      u16* __restrict__ wb,
                                                      const float* __restrict__ feature2,
                                                      u16* __restrict__ f2t,
                                                      const float* __restrict__ feature1,
                                                      u16* __restrict__ f1t,
                                                      const float* __restrict__ pos1,
                                                      const float* __restrict__ pos2,
                                                      int* __restrict__ idx_out,
                                                      float* __restrict__ w_out) {
    __shared__ __align__(16) char smem[22784];   // 16640 pk-half + 6144 warr
    int bi = blockIdx.x;
    int tid = threadIdx.x;

    if (bi >= NB_NN) {
        int ci = bi - NB_NN;
        if (ci < NB_CVT) {
            int i = ci * 256 + tid;
            if (i < 40960) {
                const float* src = (i < 24576) ? w1 : w2;
                int k = (i < 24576) ? i : (i - 24576);
                float4 v = *(const float4*)&src[(size_t)k * 4];
                ushort4 o;
                o.x = f2b(v.x); o.y = f2b(v.y); o.z = f2b(v.z); o.w = f2b(v.w);
                *(ushort4*)&wb[(size_t)i * 4] = o;
            }
            return;
        }
        // ---- transpose [B][C][S] -> [B][S][C] bf16 ----
        float (*t)[65] = (float (*)[65])smem;
        const float* in; u16* out; int C, S, s0, c0, b;
        if (ci < NB_CVT + NB_T2) {
            int lin = ci - NB_CVT;
            C = 256; S = 2048; in = feature2; out = f2t;
            s0 = (lin & 31) * 64; c0 = ((lin >> 5) & 3) * 64; b = lin >> 7;
        } else {
            int lin = ci - NB_CVT - NB_T2;
            C = 128; S = 8192; in = feature1; out = f1t;
            s0 = (lin & 127) * 64; c0 = ((lin >> 7) & 1) * 64; b = lin >> 8;
        }
        const float* ib = in + (size_t)b * C * S;
        u16* ob = out + (size_t)b * S * C;
        int col = tid & 63, r0 = tid >> 6;
#pragma unroll
        for (int p = 0; p < 16; ++p) {
            int c = p * 4 + r0;
            t[c][col] = ib[(size_t)(c0 + c) * S + s0 + col];
        }
        __syncthreads();
#pragma unroll
        for (int p = 0; p < 16; ++p) {
            int s = p * 4 + r0;
            ob[(size_t)(s0 + s) * C + c0 + col] = f2b(t[col][s]);
        }
        return;
    }

    // ---- three_nn: 64 queries/block; thread handles queries p, p+16, p+32, p+48 ----
    // Exact fp32 t' = dot - 0.5*|p2|^2; strict > keeps lowest index within a chunk;
    // merges via exact u64 keys (fmono(v)<<32 | 2047-idx): value order + low-idx ties.
    float4* pk = (float4*)smem;                          // padded: 1040 float4 = 16640 B
    u64* warr = (u64*)(smem + 16640);                    // [4 waves][16 p][4 q][3]
    int j0 = bi * 64;
    int b = j0 >> 13;
    const float* p2 = pos2 + (size_t)b * 3 * 2048;
    int p = tid & 15, ck = tid >> 4;
    int wv = tid >> 6, lane = tid & 63;
    const float* p1 = pos1 + (size_t)b * 3 * 8192;
    float qx[4], qy[4], qz[4];
#pragma unroll
    for (int t = 0; t < 4; ++t) {
        int n = (j0 & 8191) + p + t * 16;
        qx[t] = p1[n]; qy[t] = p1[8192 + n]; qz[t] = p1[16384 + n];
    }
    u64 key[4][3];
#pragma unroll
    for (int t = 0; t < 4; ++t) { key[t][0] = 0; key[t][1] = 0; key[t][2] = 0; }

    for (int half = 0; half < 2; ++half) {
        int hbase = half * 1024;
        for (int i = tid; i < 1024; i += 256) {
            int s = hbase + i;
            float x = p2[s], y = p2[2048 + s], z = p2[4096 + s];
            pk[pkix(i)] = make_float4(x, y, z, -0.5f * (x * x + y * y + z * z));
        }
        __syncthreads();

        float g[4][3]; int id[4][3];
#pragma unroll
        for (int t = 0; t < 4; ++t) {
            g[t][0] = -3.4e38f; g[t][1] = -3.4e38f; g[t][2] = -3.4e38f;
            id[t][0] = 0; id[t][1] = 0; id[t][2] = 0;
        }
        int sb = ck * 64;
        const float4* pc = pk + pkix(sb);
#pragma unroll 2
        for (int it = 0; it < 64; ++it) {
            float4 cd = pc[it];
            int s = sb + it;
#pragma unroll
            for (int t = 0; t < 4; ++t) {
                float tv = fmaf(qx[t], cd.x, fmaf(qy[t], cd.y, fmaf(qz[t], cd.z, cd.w)));
                bool c0 = tv > g[t][0], c1 = tv > g[t][1], c2 = tv > g[t][2];
                g[t][2] = c1 ? g[t][1] : (c2 ? tv : g[t][2]);
                id[t][2] = c1 ? id[t][1] : (c2 ? s : id[t][2]);
                g[t][1] = c0 ? g[t][0] : (c1 ? tv : g[t][1]);
                id[t][1] = c0 ? id[t][0] : (c1 ? s : id[t][1]);
                g[t][0] = c0 ? tv : g[t][0];
                id[t][0] = c0 ? s : id[t][0];
            }
        }
        __syncthreads();   // reads done before next half restages

#pragma unroll
        for (int t = 0; t < 4; ++t) {
#pragma unroll
            for (int r = 0; r < 3; ++r)
                ins3(((u64)fmono(g[t][r]) << 32) | (u64)(2047 - (hbase + id[t][r])),
                     key[t][0], key[t][1], key[t][2]);
        }
    }

    // in-wave merge across the 4 chunk-groups (lane>>4)
#pragma unroll
    for (int mask = 16; mask <= 32; mask <<= 1) {
#pragma unroll
        for (int t = 0; t < 4; ++t) {
            u64 m0 = shfl_xor_u64(key[t][0], mask);
            u64 m1 = shfl_xor_u64(key[t][1], mask);
            u64 m2 = shfl_xor_u64(key[t][2], mask);
            ins3(m0, key[t][0], key[t][1], key[t][2]);
            ins3(m1, key[t][0], key[t][1], key[t][2]);
            ins3(m2, key[t][0], key[t][1], key[t][2]);
        }
    }
    if (lane < 16) {
        u64* wr = &warr[(wv * 16 + p) * 12];
#pragma unroll
        for (int t = 0; t < 4; ++t) {
            wr[t * 3 + 0] = key[t][0]; wr[t * 3 + 1] = key[t][1]; wr[t * 3 + 2] = key[t][2];
        }
    }
    __syncthreads();
    if (tid < 64) {
        int pp = tid & 15, t = tid >> 4;
        const u64* w0 = &warr[pp * 12 + t * 3];
        u64 k0 = w0[0], k1 = w0[1], k2 = w0[2];
#pragma unroll
        for (int w = 1; w < 4; ++w) {
            const u64* wr = &warr[(w * 16 + pp) * 12 + t * 3];
            ins3(wr[0], k0, k1, k2);
            ins3(wr[1], k0, k1, k2);
            ins3(wr[2], k0, k1, k2);
        }
        int s0 = 2047 - (int)(k0 & 0xFFFFFFFFu);
        int s1 = 2047 - (int)(k1 & 0xFFFFFFFFu);
        int s2 = 2047 - (int)(k2 & 0xFFFFFFFFu);
        int j = j0 + pp + t * 16;
        int n = j & 8191;
        float x1 = p1[n], y1 = p1[8192 + n], z1 = p1[16384 + n];
        float n1 = x1 * x1 + y1 * y1 + z1 * z1;
        float X0 = p2[s0], Y0 = p2[2048 + s0], Z0 = p2[4096 + s0];
        float X1 = p2[s1], Y1v = p2[2048 + s1], Z1 = p2[4096 + s1];
        float X2 = p2[s2], Y2v = p2[2048 + s2], Z2 = p2[4096 + s2];
        float t0 = x1 * X0 + y1 * Y0 + z1 * Z0 - 0.5f * (X0 * X0 + Y0 * Y0 + Z0 * Z0);
        float t1 = x1 * X1 + y1 * Y1v + z1 * Z1 - 0.5f * (X1 * X1 + Y1v * Y1v + Z1 * Z1);
        float t2 = x1 * X2 + y1 * Y2v + z1 * Z2 - 0.5f * (X2 * X2 + Y2v * Y2v + Z2 * Z2);
        float d0 = fmaxf(fmaf(-2.f, t0, n1), 1e-10f);
        float d1 = fmaxf(fmaf(-2.f, t1, n1), 1e-10f);
        float d2 = fmaxf(fmaf(-2.f, t2, n1), 1e-10f);
        float w0v = 1.f / d0, w1v = 1.f / d1, w2v = 1.f / d2;
        float inv = 1.f / (w0v + w1v + w2v);
        idx_out[j * 3] = s0; idx_out[j * 3 + 1] = s1; idx_out[j * 3 + 2] = s2;
        w_out[j * 3] = w0v * inv; w_out[j * 3 + 1] = w1v * inv; w_out[j * 3 + 2] = w2v * inv;
    }
}

// ---------- GEMM: Yb[j][m] = bf16(sum_k A[j][k]*Bw[m][k] + bias[m]), fused BN stats ----------
// GATHER: k<256 A-tile built on the fly = interp gather from F2T (idx/wgt in regs);
//         k>=256 A from F1T (stride 128) via async copy.
// FUSE:   A = relu(bn1(Y1)) applied in-register during staging (BN table in LDS).
// Epilogue: LDS bounce (stride 136) -> fully coalesced u16x8 stores of the Y tile.
template <int KT, bool GATHER, bool FUSE>
__global__ __launch_bounds__(256, 2) void gemm_kernel(const u16* __restrict__ A1,
                                                      const u16* __restrict__ A2,
                                                      const u16* __restrict__ Bw,
                                                      const float* __restrict__ bias,
                                                      const int* __restrict__ idx,
                                                      const float* __restrict__ wgt,
                                                      const float* __restrict__ stats_in,
                                                      const float* __restrict__ g_in,
                                                      const float* __restrict__ be_in,
                                                      u16* __restrict__ Yb,
                                                      float* __restrict__ stats) {
    __shared__ __align__(16) char smemA[36864];
    u16* Al = (u16*)smemA;                       // [128][64], k-loop
    u16* Bl = (u16*)(smemA + 16384);             // [128][64], k-loop
    u16* T  = (u16*)smemA;                       // [128][136] epilogue bounce (overlays Al/Bl)
    float2* BNT = (float2*)(smemA + 34816);      // 256 x (scale, shift), FUSE only
    int tid = threadIdx.x;
    int lane = tid & 63, wv = tid >> 6;
    int j0 = blockIdx.x * 128, m0 = blockIdx.y * 128;
    int l15 = lane & 15, q = lane >> 4;
    int wj = (wv >> 1) * 64, wm = (wv & 1) * 64;
    f32x4 acc[4][4];
#pragma unroll
    for (int i = 0; i < 4; ++i)
#pragma unroll
        for (int jj = 0; jj < 4; ++jj) acc[i][jj] = (f32x4){0.f, 0.f, 0.f, 0.f};

    int rbase = wv * 32;
    int lrow = lane >> 3, lchunk = lane & 7;
    const u16* Bg = Bw + (size_t)m0 * KT;

    if (FUSE) {
        int m = tid;
        const float inv = 1.f / 32768.f;
        float mean = stats_in[m] * inv;
        float var = stats_in[256 + m] * inv - mean * mean;
        float a = g_in[m] * rsqrtf(var + 1e-5f);
        BNT[m] = make_float2(a, be_in[m] - mean * a);
        __syncthreads();
    }

    // GATHER: hoist this thread's 4 rows' idx/wgt + row base pointers into registers
    const u16* grow0[4]; const u16* grow1[4]; const u16* grow2[4];
    float gw0[4], gw1[4], gw2[4];
    if (GATHER) {
#pragma unroll
        for (int qq = 0; qq < 4; ++qq) {
            int jl = rbase + qq * 8 + lrow;
            int j = j0 + jl;
            int bb = j >> 13;
            const u16* fb = A1 + (size_t)bb * 2048 * 256;   // A1 = F2T
            grow0[qq] = fb + (size_t)idx[j * 3 + 0] * 256;
            grow1[qq] = fb + (size_t)idx[j * 3 + 1] * 256;
            grow2[qq] = fb + (size_t)idx[j * 3 + 2] * 256;
            gw0[qq] = wgt[j * 3 + 0]; gw1[qq] = wgt[j * 3 + 1]; gw2[qq] = wgt[j * 3 + 2];
        }
    }

    for (int k0 = 0; k0 < KT; k0 += 64) {
        if (GATHER && k0 < 256) {
            int c = k0 + lchunk * 8;
#pragma unroll
            for (int qq = 0; qq < 4; ++qq) {
                int row = rbase + qq * 8;
                u16x8 v0 = *(const u16x8*)(grow0[qq] + c);
                u16x8 v1 = *(const u16x8*)(grow1[qq] + c);
                u16x8 v2 = *(const u16x8*)(grow2[qq] + c);
                u16x8 o;
#pragma unroll
                for (int e = 0; e < 8; ++e)
                    o[e] = f2b(gw0[qq] * b2f(v0[e]) + gw1[qq] * b2f(v1[e]) + gw2[qq] * b2f(v2[e]));
                *(u16x8*)&Al[(row + lrow) * 64 + lchunk * 8] = o;
                async_cp16(&Bl[row * 64], Bg + (size_t)(row + lrow) * KT + k0 + lchunk * 8);
            }
        } else if (FUSE) {
            int c = k0 + lchunk * 8;
            float2 bn[8];
#pragma unroll
            for (int e = 0; e < 8; ++e) bn[e] = BNT[c + e];
#pragma unroll
            for (int qq = 0; qq < 4; ++qq) {
                int row = rbase + qq * 8;
                u16x8 y = *(const u16x8*)&A1[(size_t)(j0 + row + lrow) * 256 + c];
                u16x8 o;
#pragma unroll
                for (int e = 0; e < 8; ++e)
                    o[e] = f2b(fmaxf(b2f(y[e]) * bn[e].x + bn[e].y, 0.f));
                *(u16x8*)&Al[(row + lrow) * 64 + lchunk * 8] = o;
                async_cp16(&Bl[row * 64], Bg + (size_t)(row + lrow) * KT + k0 + lchunk * 8);
            }
        } else {
            // k >= 256 region of GATHER gemm: A from F1T, stride 128
            const u16* src = A2 + (size_t)j0 * 128 + (k0 - 256);
#pragma unroll
            for (int qq = 0; qq < 4; ++qq) {
                int row = rbase + qq * 8;   // wave-uniform LDS base; HW adds lane*16B
                async_cp16(&Al[row * 64], src + (size_t)(row + lrow) * 128 + lchunk * 8);
                async_cp16(&Bl[row * 64], Bg + (size_t)(row + lrow) * KT + k0 + lchunk * 8);
            }
        }
        __syncthreads();
#pragma unroll
        for (int ks = 0; ks < 2; ++ks) {
            bf16x8 af[4], bfr[4];
#pragma unroll
            for (int i = 0; i < 4; ++i)
                af[i] = *(const bf16x8*)&Al[(wj + i * 16 + l15) * 64 + ks * 32 + q * 8];
#pragma unroll
            for (int i = 0; i < 4; ++i)
                bfr[i] = *(const bf16x8*)&Bl[(wm + i * 16 + l15) * 64 + ks * 32 + q * 8];
#pragma unroll
            for (int i = 0; i < 4; ++i)
#pragma unroll
                for (int jj = 0; jj < 4; ++jj)
                    acc[i][jj] = __builtin_amdgcn_mfma_f32_16x16x32_bf16(af[i], bfr[jj],
                                                                         acc[i][jj], 0, 0, 0);
        }
        __syncthreads();
    }
    // epilogue: stats + bf16 tile into LDS (D col = lane&15 -> m, row = q*4+reg -> j)
#pragma unroll
    for (int jj = 0; jj < 4; ++jj) {
        int ml = wm + jj * 16 + l15;
        float bv = bias[m0 + ml];
        float s = 0.f, s2 = 0.f;
#pragma unroll
        for (int i = 0; i < 4; ++i) {
            int jl = wj + i * 16 + q * 4;
#pragma unroll
            for (int r = 0; r < 4; ++r) {
                float v = acc[i][jj][r] + bv;
                s += v; s2 += v * v;
                T[(jl + r) * 136 + ml] = f2b(v);
            }
        }
        s += __shfl_xor(s, 16); s += __shfl_xor(s, 32);
        s2 += __shfl_xor(s2, 16); s2 += __shfl_xor(s2, 32);
        if (q == 0) {
            atomicAdd(&stats[m0 + ml], s);
            atomicAdd(&stats[256 + m0 + ml], s2);
        }
    }
    __syncthreads();
    // coalesced store: each wave covers 4 rows x 128 ch per iter (256 B segments)
#pragma unroll
    for (int it = 0; it < 8; ++it) {
        int jl = it * 16 + wv * 4 + q;
        u16x8 v = *(const u16x8*)&T[jl * 136 + l15 * 8];
        *(u16x8*)&Yb[(size_t)(j0 + jl) * 256 + m0 + l15 * 8] = v;
    }
}

// ---------- BN2+ReLU (inline finalize) + transpose [j][o] -> out[b][o][n] ----------
__global__ __launch_bounds__(256) void final_out_kernel(const u16* __restrict__ Y2,
                                                        const float* __restrict__ stats,
                                                        const float* __restrict__ g,
                                                        const float* __restrict__ be,
                                                        float* __restrict__ out) {
    __shared__ float t[64][65];
    int j0 = blockIdx.x * 64, o0 = blockIdx.y * 64;
    int tid = threadIdx.x;
    int c4 = (tid & 15) * 4, rw = tid >> 4;
#pragma unroll
    for (int p = 0; p < 4; ++p) {
        int jl = p * 16 + rw;
        ushort4 v = *(const ushort4*)&Y2[(size_t)(j0 + jl) * 256 + o0 + c4];
        t[jl][c4] = b2f(v.x); t[jl][c4 + 1] = b2f(v.y);
        t[jl][c4 + 2] = b2f(v.z); t[jl][c4 + 3] = b2f(v.w);
    }
    __syncthreads();
    int b = j0 >> 13, n0 = j0 & 8191;
    const float inv = 1.f / 32768.f;
#pragma unroll
    for (int p = 0; p < 4; ++p) {
        int ol = p * 16 + rw;
        int o = o0 + ol;
        float mean = stats[o] * inv;
        float var = stats[256 + o] * inv - mean * mean;
        float a = g[o] * rsqrtf(var + 1e-5f);
        float s = be[o] - mean * a;
        float4 v;
        v.x = fmaxf(t[c4][ol] * a + s, 0.f);
        v.y = fmaxf(t[c4 + 1][ol] * a + s, 0.f);
        v.z = fmaxf(t[c4 + 2][ol] * a + s, 0.f);
        v.w = fmaxf(t[c4 + 3][ol] * a + s, 0.f);
        *(float4*)&out[(size_t)b * 2097152 + (size_t)o * 8192 + n0 + c4] = v;
    }
}

extern "C" void kernel_launch(void* const* d_in, const int* in_sizes, int n_in,
                              void* d_out, int out_size, void* d_ws, size_t ws_size,
                              hipStream_t stream) {
    const float* pos1 = (const float*)d_in[0];
    const float* pos2 = (const float*)d_in[1];
    const float* feature1 = (const float*)d_in[2];
    const float* feature2 = (const float*)d_in[3];
    const float* W1 = (const float*)d_in[4];
    const float* b1 = (const float*)d_in[5];
    const float* g1 = (const float*)d_in[6];
    const float* be1 = (const float*)d_in[7];
    const float* W2 = (const float*)d_in[8];
    const float* b2 = (const float*)d_in[9];
    const float* g2 = (const float*)d_in[10];
    const float* be2 = (const float*)d_in[11];

    char* ws = (char*)d_ws;
    int*   IDX    = (int*)(ws + 0);                 // 393216 B
    float* WGT    = (float*)(ws + 393216);          // 393216 B
    u16*   W1B    = (u16*)(ws + 786432);            // 196608 B
    u16*   W2B    = (u16*)(ws + 983040);            // 131072 B (contiguous after W1B)
    float* STATS  = (float*)(ws + 1114112);         // 4096 B: sum1/sq1/sum2/sq2
    u16*   F2T    = (u16*)(ws + 1118208);           // 4 MiB  [4][2048][256]
    u16*   F1T    = (u16*)(ws + 5312512);           // 8 MiB  [4][8192][128]
    u16*   Y1     = (u16*)(ws + 13701120);          // 16 MiB [32768][256]
    u16*   Y2     = (u16*)(ws + 30478336);          // 16 MiB
    float* OUT    = (float*)d_out;

    hipMemsetAsync(STATS, 0, 1024 * sizeof(float), stream);
    prep_kernel<<<NB_NN + NB_CVT + NB_T2 + NB_T1, 256, 0, stream>>>(
        W1, W2, W1B, feature2, F2T, feature1, F1T, pos1, pos2, IDX, WGT);
    gemm_kernel<384, true, false><<<dim3(256, 2), 256, 0, stream>>>(
        F2T, F1T, W1B, b1, IDX, WGT, nullptr, nullptr, nullptr, Y1, STATS);
    gemm_kernel<256, false, true><<<dim3(256, 2), 256, 0, stream>>>(
        Y1, nullptr, W2B, b2, nullptr, nullptr, STATS, g1, be1, Y2, STATS + 512);
    final_out_kernel<<<dim3(512, 4), 256, 0, stream>>>(Y2, STATS + 512, g2, be2, OUT);
}